// Round 2
// baseline (3333.123 us; speedup 1.0000x reference)
//
#include <hip/hip_runtime.h>
#include <hip/hip_bf16.h>
#include <math.h>

// Problem constants: B=2, S=2048, E=2048, HEADS=16, d=128
#define PB 2
#define PS 2048
#define PE 2048
#define PH 16
#define PD 128
#define PN_PROJ 6160   // 3*E + HEADS
#define PM 4096        // B*S

// ---------------------------------------------------------------------------
// Generic fp32 GEMM: C[M,N] = A[M,K] @ B[K,N], row-major, 128x128 tile,
// 8x8 per thread, transposed-A LDS tile for vector reads.
// M, K assumed multiples of tile sizes; N guarded.
// ---------------------------------------------------------------------------
__global__ __launch_bounds__(256) void gemm_f32(
    const float* __restrict__ A, const float* __restrict__ B, float* __restrict__ C,
    int M, int N, int K, int lda, int ldb, int ldc) {
  __shared__ float As[16][128];   // [k][m] transposed
  __shared__ float Bs[16][128];   // [k][n]
  const int tid = threadIdx.x;
  const int tx = tid & 15, ty = tid >> 4;
  const int mBase = blockIdx.y * 128, nBase = blockIdx.x * 128;

  float acc[8][8];
#pragma unroll
  for (int i = 0; i < 8; ++i)
#pragma unroll
    for (int j = 0; j < 8; ++j) acc[i][j] = 0.f;

  for (int kt = 0; kt < K; kt += 16) {
    // stage A tile (128 rows x 16 k), store transposed
#pragma unroll
    for (int i = 0; i < 2; ++i) {
      int l = i * 256 + tid;            // 512 float4
      int row = l >> 2, k4 = (l & 3) * 4;
      float4 a = *reinterpret_cast<const float4*>(&A[(size_t)(mBase + row) * lda + kt + k4]);
      As[k4 + 0][row] = a.x; As[k4 + 1][row] = a.y;
      As[k4 + 2][row] = a.z; As[k4 + 3][row] = a.w;
    }
    // stage B tile (16 k x 128 n)
#pragma unroll
    for (int i = 0; i < 2; ++i) {
      int l = i * 256 + tid;
      int kr = l >> 5, c4 = (l & 31) * 4;
      int col = nBase + c4;
      float4 bv = make_float4(0.f, 0.f, 0.f, 0.f);
      if (col < N) bv = *reinterpret_cast<const float4*>(&B[(size_t)(kt + kr) * ldb + col]);
      *reinterpret_cast<float4*>(&Bs[kr][c4]) = bv;
    }
    __syncthreads();
#pragma unroll
    for (int k = 0; k < 16; ++k) {
      float a[8], b[8];
      *reinterpret_cast<float4*>(&a[0]) = *reinterpret_cast<const float4*>(&As[k][ty * 8]);
      *reinterpret_cast<float4*>(&a[4]) = *reinterpret_cast<const float4*>(&As[k][ty * 8 + 4]);
      *reinterpret_cast<float4*>(&b[0]) = *reinterpret_cast<const float4*>(&Bs[k][tx * 8]);
      *reinterpret_cast<float4*>(&b[4]) = *reinterpret_cast<const float4*>(&Bs[k][tx * 8 + 4]);
#pragma unroll
      for (int i = 0; i < 8; ++i)
#pragma unroll
        for (int j = 0; j < 8; ++j) acc[i][j] += a[i] * b[j];
    }
    __syncthreads();
  }
#pragma unroll
  for (int i = 0; i < 8; ++i) {
    int row = mBase + ty * 8 + i;
#pragma unroll
    for (int j2 = 0; j2 < 2; ++j2) {
      int col = nBase + tx * 8 + j2 * 4;
      if (col < N) {
        float4 v = make_float4(acc[i][j2 * 4], acc[i][j2 * 4 + 1],
                               acc[i][j2 * 4 + 2], acc[i][j2 * 4 + 3]);
        *reinterpret_cast<float4*>(&C[(size_t)row * ldc + col]) = v;
      }
    }
  }
}

// ---------------------------------------------------------------------------
// tanh gate: hgbuf[b][h][s] = tanh(proj[b*S+s][3E + h])
// ---------------------------------------------------------------------------
__global__ __launch_bounds__(256) void hg_kernel(const float* __restrict__ proj,
                                                 float* __restrict__ hgbuf) {
  int idx = blockIdx.x * 256 + threadIdx.x;  // over B*H*S = 65536
  int s = idx & (PS - 1);
  int bh = idx >> 11;
  int h = bh & (PH - 1), b = bh >> 4;
  float v = proj[(size_t)(b * PS + s) * PN_PROJ + 3 * PE + h];
  hgbuf[idx] = tanhf(v);
}

// ---------------------------------------------------------------------------
// Kc = cumsum_j ((j+1) * hg[j] * K[j]) / (i+1)^2 over sequence axis.
// Two-pass chunked scan, chunk = 128 rows. Kc written in place over K slots.
// Grid: B*H*16 chunks, block = 128 threads (one per d).
// ---------------------------------------------------------------------------
__global__ __launch_bounds__(128) void kc_pass1(const float* __restrict__ proj,
                                                const float* __restrict__ hgbuf,
                                                float* __restrict__ csum) {
  int c = blockIdx.x & 15, bh = blockIdx.x >> 4;
  int h = bh & (PH - 1), b = bh >> 4;
  int d = threadIdx.x;
  __shared__ float hgs[128];
  hgs[d] = hgbuf[bh * PS + c * 128 + d];
  __syncthreads();
  const float* kbase = proj + (size_t)(b * PS) * PN_PROJ + h * (3 * PD) + PD + d;
  float acc = 0.f;
  int j0 = c * 128;
  for (int i = 0; i < 128; ++i) {
    int j = j0 + i;
    acc += (float)(j + 1) * hgs[i] * kbase[(size_t)j * PN_PROJ];
  }
  csum[blockIdx.x * 128 + d] = acc;
}

__global__ __launch_bounds__(128) void kc_pass2(float* __restrict__ proj,
                                                const float* __restrict__ hgbuf,
                                                const float* __restrict__ csum) {
  int c = blockIdx.x & 15, bh = blockIdx.x >> 4;
  int h = bh & (PH - 1), b = bh >> 4;
  int d = threadIdx.x;
  __shared__ float hgs[128];
  hgs[d] = hgbuf[bh * PS + c * 128 + d];
  __syncthreads();
  float acc = 0.f;
  for (int cc = 0; cc < c; ++cc) acc += csum[(bh * 16 + cc) * 128 + d];
  float* kbase = proj + (size_t)(b * PS) * PN_PROJ + h * (3 * PD) + PD + d;
  int j0 = c * 128;
  for (int i = 0; i < 128; ++i) {
    int j = j0 + i;
    acc += (float)(j + 1) * hgs[i] * kbase[(size_t)j * PN_PROJ];
    float t = (float)(j + 1);
    kbase[(size_t)j * PN_PROJ] = acc / (t * t);
  }
}

// ---------------------------------------------------------------------------
// Flash attention fp32. Block = (bh, q-tile of 32 rows), 256 threads.
// thread (ty 0..7, tx 0..31): rows r = ty*4+i, S col c = tx, O cols tx*4+j.
// Causal: only kt <= qt tiles. Output written as (b, s, h*128+d).
// S=2048 -> 64 q-tiles per (b,h).  [R1 fix: was &31/>>5 -> aliased blocks,
// rows 1024..2047 per head never computed]
// ---------------------------------------------------------------------------
__global__ __launch_bounds__(256) void attn_f32(const float* __restrict__ proj,
                                                float* __restrict__ O) {
  const int qt = blockIdx.x & 63;
  const int bh = blockIdx.x >> 6;
  const int h = bh & (PH - 1), b = bh >> 4;
  const int tid = threadIdx.x;
  const int tx = tid & 31, ty = tid >> 5;
  const int q0 = qt * 32;

  __shared__ float Qs[32][136];
  __shared__ float Ks[32][132];
  __shared__ float Vs[32][132];
  __shared__ float Ps[32][33];

  const float* base = proj + (size_t)(b * PS) * PN_PROJ + h * (3 * PD);

  // load Q tile
#pragma unroll
  for (int i = 0; i < 4; ++i) {
    int l = i * 256 + tid;              // 1024 float4 = 32x128
    int r = l >> 5, c4 = (l & 31) * 4;
    float4 v = *reinterpret_cast<const float4*>(&base[(size_t)(q0 + r) * PN_PROJ + c4]);
    *reinterpret_cast<float4*>(&Qs[r][c4]) = v;
  }

  float m_r[4], l_r[4], o_acc[4][4];
#pragma unroll
  for (int i = 0; i < 4; ++i) {
    m_r[i] = -INFINITY; l_r[i] = 0.f;
#pragma unroll
    for (int j = 0; j < 4; ++j) o_acc[i][j] = 0.f;
  }
  const float scale = 1.0f / sqrtf((float)PE);

  for (int kt = 0; kt <= qt; ++kt) {
    __syncthreads();  // Ks/Vs/Ps safe to overwrite; also covers Q staging
    // load Kc + V tiles
#pragma unroll
    for (int i = 0; i < 4; ++i) {
      int l = i * 256 + tid;
      int r = l >> 5, c4 = (l & 31) * 4;
      const float* rowp = &base[(size_t)(kt * 32 + r) * PN_PROJ];
      *reinterpret_cast<float4*>(&Ks[r][c4]) = *reinterpret_cast<const float4*>(&rowp[PD + c4]);
      *reinterpret_cast<float4*>(&Vs[r][c4]) = *reinterpret_cast<const float4*>(&rowp[2 * PD + c4]);
    }
    __syncthreads();

    // S[r][tx] = Q[r] . Kc[tx]
    float sv[4] = {0.f, 0.f, 0.f, 0.f};
#pragma unroll 4
    for (int k4 = 0; k4 < 128; k4 += 4) {
      float4 kv = *reinterpret_cast<const float4*>(&Ks[tx][k4]);
#pragma unroll
      for (int i = 0; i < 4; ++i) {
        float4 qv = *reinterpret_cast<const float4*>(&Qs[ty * 4 + i][k4]);
        sv[i] += qv.x * kv.x + qv.y * kv.y + qv.z * kv.z + qv.w * kv.w;
      }
    }

    // online softmax update
#pragma unroll
    for (int i = 0; i < 4; ++i) {
      int r = ty * 4 + i;
      float s = sv[i] * scale;
      if (kt == qt && tx > r) s = -INFINITY;
      float mloc = s;
      for (int off = 16; off > 0; off >>= 1) mloc = fmaxf(mloc, __shfl_xor(mloc, off, 64));
      float mnew = fmaxf(m_r[i], mloc);
      float alpha = expf(m_r[i] - mnew);   // exp(-inf)=0 on first tile
      float p = expf(s - mnew);            // masked -> 0
      float lsum = p;
      for (int off = 16; off > 0; off >>= 1) lsum += __shfl_xor(lsum, off, 64);
      l_r[i] = l_r[i] * alpha + lsum;
      m_r[i] = mnew;
      Ps[r][tx] = p;
#pragma unroll
      for (int j = 0; j < 4; ++j) o_acc[i][j] *= alpha;
    }
    __syncthreads();

    // O[r][tx*4+j] += sum_c Ps[r][c] * Vs[c][tx*4+j]
#pragma unroll 4
    for (int c = 0; c < 32; ++c) {
      float4 vv = *reinterpret_cast<const float4*>(&Vs[c][tx * 4]);
#pragma unroll
      for (int i = 0; i < 4; ++i) {
        float p = Ps[ty * 4 + i][c];
        o_acc[i][0] += p * vv.x; o_acc[i][1] += p * vv.y;
        o_acc[i][2] += p * vv.z; o_acc[i][3] += p * vv.w;
      }
    }
  }

  // normalize + store to (b, s, h*128 + d)
#pragma unroll
  for (int i = 0; i < 4; ++i) {
    int r = ty * 4 + i;
    float inv = 1.0f / l_r[i];
    float4 v = make_float4(o_acc[i][0] * inv, o_acc[i][1] * inv,
                           o_acc[i][2] * inv, o_acc[i][3] * inv);
    *reinterpret_cast<float4*>(&O[(size_t)(b * PS + q0 + r) * PE + h * PD + tx * 4]) = v;
  }
}

// ---------------------------------------------------------------------------
extern "C" void kernel_launch(void* const* d_in, const int* in_sizes, int n_in,
                              void* d_out, int out_size, void* d_ws, size_t ws_size,
                              hipStream_t stream) {
  const float* x     = (const float*)d_in[0];   // (B,S,E)
  const float* Wqkvh = (const float*)d_in[1];   // (E, 3E+H)
  const float* Wout  = (const float*)d_in[2];   // (E, E)
  float* out = (float*)d_out;                   // (B,S,E)
  float* ws = (float*)d_ws;

  const size_t PROJ_ELEMS = (size_t)PM * PN_PROJ;        // 25,231,360
  const size_t O_ELEMS    = (size_t)PM * PE;             //  8,388,608
  const size_t HG_ELEMS   = (size_t)PB * PH * PS;        //     65,536

  float* proj  = ws;
  float* Oattn = ws + PROJ_ELEMS;
  float* hgbuf = Oattn + O_ELEMS;
  float* csum  = hgbuf + HG_ELEMS;

  // 1) proj = x @ W_qkvh : (4096 x 6160), K=2048
  {
    dim3 grid((PN_PROJ + 127) / 128, PM / 128);
    gemm_f32<<<grid, 256, 0, stream>>>(x, Wqkvh, proj, PM, PN_PROJ, PE, PE, PN_PROJ, PN_PROJ);
  }
  // 2) gate + chunked causal weighted cumsum (Kc in place over K slots)
  hg_kernel<<<(PB * PH * PS) / 256, 256, 0, stream>>>(proj, hgbuf);
  kc_pass1<<<PB * PH * 16, 128, 0, stream>>>(proj, hgbuf, csum);
  kc_pass2<<<PB * PH * 16, 128, 0, stream>>>(proj, hgbuf, csum);
  // 3) flash attention -> Oattn in (b, s, h*d) layout
  attn_f32<<<PB * PH * (PS / 32), 256, 0, stream>>>(proj, Oattn);
  // 4) out = Oattn @ W_out : (4096 x 2048), K=2048
  {
    dim3 grid(PE / 128, PM / 128);
    gemm_f32<<<grid, 256, 0, stream>>>(Oattn, Wout, out, PM, PE, PE, PE, PE, PE);
  }
}

// Round 3
// 1705.473 us; speedup vs baseline: 1.9544x; 1.9544x over previous
//
#include <hip/hip_runtime.h>
#include <hip/hip_bf16.h>
#include <math.h>

// Problem constants: B=2, S=2048, E=2048, HEADS=16, d=128
#define PB 2
#define PS 2048
#define PE 2048
#define PH 16
#define PD 128
#define PN_PROJ 6160   // 3*E + HEADS
#define PM 4096        // B*S
#define PQKV 6144      // 3*E (MFMA-tiled part of GEMM1)

typedef __attribute__((ext_vector_type(8))) short bf16x8;
typedef __attribute__((ext_vector_type(4))) float f32x4;

__device__ __forceinline__ void gload_lds16(const void* g, void* l) {
  __builtin_amdgcn_global_load_lds((const __attribute__((address_space(1))) void*)g,
                                   (__attribute__((address_space(3))) void*)l, 16, 0, 0);
}

// ---------------------------------------------------------------------------
// bf16 MFMA GEMM (m97 structure): C[M,N](f32) = A[M,K](bf16,row-major)
//   @ Bt[N,K](bf16, row-major = B transposed).
// 128x128 tile, BK=32, 256 thr = 4 waves (2x2 of 64x64), 4x4 frags of 16x16x32.
// Grid must exactly tile M,N. lda = ldb = K.
// ---------------------------------------------------------------------------
__global__ __launch_bounds__(256) void gemm_bf16_bt(
    const __hip_bfloat16* __restrict__ A, const __hip_bfloat16* __restrict__ Bt,
    float* __restrict__ C, int K, int ldc) {
  __shared__ __align__(16) __hip_bfloat16 As[128 * 32];  // [row][k] 8KB
  __shared__ __align__(16) __hip_bfloat16 Bs[128 * 32];  // [n][k]   8KB
  const int tid = threadIdx.x;
  const int wave = tid >> 6, lane = tid & 63;
  const int wr = wave >> 1, wc = wave & 1;     // wave sub-tile (64x64)
  const int fr = lane & 15, fq = lane >> 4;    // fragment row/col, k-quad
  const int mBase = blockIdx.y * 128, nBase = blockIdx.x * 128;
  const int rSeg = lane >> 2;                  // 0..15 row-in-segment
  const int k8 = (lane & 3) * 8;               // 0,8,16,24

  f32x4 acc[4][4];
#pragma unroll
  for (int m = 0; m < 4; ++m)
#pragma unroll
    for (int n = 0; n < 4; ++n) acc[m][n] = (f32x4){0.f, 0.f, 0.f, 0.f};

  for (int kt = 0; kt < K; kt += 32) {
    __syncthreads();  // all waves done reading previous tile
#pragma unroll
    for (int i = 0; i < 2; ++i) {
      int seg = i * 4 + wave;                  // 0..7, 16 rows each
      int row = seg * 16 + rSeg;
      gload_lds16(&A[(size_t)(mBase + row) * K + kt + k8], &As[seg * 512]);
      gload_lds16(&Bt[(size_t)(nBase + row) * K + kt + k8], &Bs[seg * 512]);
    }
    __syncthreads();  // staging complete (compiler drains vmcnt before barrier)

    bf16x8 av[4], bv[4];
#pragma unroll
    for (int m = 0; m < 4; ++m)
      av[m] = *(const bf16x8*)&As[(wr * 64 + m * 16 + fr) * 32 + fq * 8];
#pragma unroll
    for (int n = 0; n < 4; ++n)
      bv[n] = *(const bf16x8*)&Bs[(wc * 64 + n * 16 + fr) * 32 + fq * 8];
#pragma unroll
    for (int m = 0; m < 4; ++m)
#pragma unroll
      for (int n = 0; n < 4; ++n)
        acc[m][n] = __builtin_amdgcn_mfma_f32_16x16x32_bf16(av[m], bv[n], acc[m][n], 0, 0, 0);
  }

  // C/D layout (m89-verified): col = lane&15, row = (lane>>4)*4 + reg
#pragma unroll
  for (int m = 0; m < 4; ++m) {
#pragma unroll
    for (int n = 0; n < 4; ++n) {
      int row0 = mBase + wr * 64 + m * 16 + fq * 4;
      int col = nBase + wc * 64 + n * 16 + fr;
#pragma unroll
      for (int j = 0; j < 4; ++j)
        C[(size_t)(row0 + j) * ldc + col] = acc[m][n][j];
    }
  }
}

// ---------------------------------------------------------------------------
// cast fp32 -> bf16, 4 elems/thread
// ---------------------------------------------------------------------------
__global__ __launch_bounds__(256) void cast_f32_bf16(const float* __restrict__ in,
                                                     __hip_bfloat16* __restrict__ out,
                                                     int n4) {
  int i = blockIdx.x * 256 + threadIdx.x;
  if (i >= n4) return;
  float4 v = ((const float4*)in)[i];
  union { __hip_bfloat16 h[4]; uint2 u; } pk;
  pk.h[0] = __float2bfloat16(v.x); pk.h[1] = __float2bfloat16(v.y);
  pk.h[2] = __float2bfloat16(v.z); pk.h[3] = __float2bfloat16(v.w);
  ((uint2*)out)[i] = pk.u;
}

// ---------------------------------------------------------------------------
// transpose + cast: Wt[n][k] = bf16(W[k][nOff+n]); 32x32 LDS tiles.
// grid = (cols/32, rows/32), block = 256.
// ---------------------------------------------------------------------------
__global__ __launch_bounds__(256) void transpose_cast(const float* __restrict__ W,
                                                      __hip_bfloat16* __restrict__ Wt,
                                                      int ldw, int ldt, int nOff) {
  __shared__ float t[32][33];
  int nb = blockIdx.x * 32, kb = blockIdx.y * 32;
  int tx = threadIdx.x & 31, ty = threadIdx.x >> 5;  // ty 0..7
#pragma unroll
  for (int i = 0; i < 4; ++i) {
    int k = ty + i * 8;
    t[k][tx] = W[(size_t)(kb + k) * ldw + nOff + nb + tx];
  }
  __syncthreads();
#pragma unroll
  for (int i = 0; i < 4; ++i) {
    int n = ty + i * 8;
    Wt[(size_t)(nb + n) * ldt + kb + tx] = __float2bfloat16(t[tx][n]);
  }
}

// ---------------------------------------------------------------------------
// Gate head from x directly (fp32): hgbuf[(b*H+h)*S+s] = tanh(x[bs,:] . W[:,3E+h])
// One block per (b,s) row.
// ---------------------------------------------------------------------------
__global__ __launch_bounds__(256) void hg_from_x(const float* __restrict__ x,
                                                 const float* __restrict__ W,
                                                 float* __restrict__ hgbuf) {
  int bs = blockIdx.x;                 // 0..4095
  int b = bs >> 11, s = bs & (PS - 1);
  __shared__ float xs[PE];
  __shared__ float red[16][17];
  const float* xr = x + (size_t)bs * PE;
  for (int i = threadIdx.x; i < PE / 4; i += 256)
    *(float4*)&xs[i * 4] = ((const float4*)xr)[i];
  __syncthreads();
  int h = threadIdx.x & 15, part = threadIdx.x >> 4;
  float acc = 0.f;
  for (int k = part * 128; k < part * 128 + 128; ++k)
    acc += xs[k] * W[(size_t)k * PN_PROJ + 3 * PE + h];
  red[part][h] = acc;
  __syncthreads();
  if (threadIdx.x < 16) {
    float sm = 0.f;
#pragma unroll
    for (int p = 0; p < 16; ++p) sm += red[p][threadIdx.x];
    hgbuf[(size_t)(b * PH + threadIdx.x) * PS + s] = tanhf(sm);
  }
}

// ---------------------------------------------------------------------------
// Kc scan (unchanged, fp32 in proj K slots)
// ---------------------------------------------------------------------------
__global__ __launch_bounds__(128) void kc_pass1(const float* __restrict__ proj,
                                                const float* __restrict__ hgbuf,
                                                float* __restrict__ csum) {
  int c = blockIdx.x & 15, bh = blockIdx.x >> 4;
  int h = bh & (PH - 1), b = bh >> 4;
  int d = threadIdx.x;
  __shared__ float hgs[128];
  hgs[d] = hgbuf[bh * PS + c * 128 + d];
  __syncthreads();
  const float* kbase = proj + (size_t)(b * PS) * PN_PROJ + h * (3 * PD) + PD + d;
  float acc = 0.f;
  int j0 = c * 128;
  for (int i = 0; i < 128; ++i) {
    int j = j0 + i;
    acc += (float)(j + 1) * hgs[i] * kbase[(size_t)j * PN_PROJ];
  }
  csum[blockIdx.x * 128 + d] = acc;
}

__global__ __launch_bounds__(128) void kc_pass2(float* __restrict__ proj,
                                                const float* __restrict__ hgbuf,
                                                const float* __restrict__ csum) {
  int c = blockIdx.x & 15, bh = blockIdx.x >> 4;
  int h = bh & (PH - 1), b = bh >> 4;
  int d = threadIdx.x;
  __shared__ float hgs[128];
  hgs[d] = hgbuf[bh * PS + c * 128 + d];
  __syncthreads();
  float acc = 0.f;
  for (int cc = 0; cc < c; ++cc) acc += csum[(bh * 16 + cc) * 128 + d];
  float* kbase = proj + (size_t)(b * PS) * PN_PROJ + h * (3 * PD) + PD + d;
  int j0 = c * 128;
  for (int i = 0; i < 128; ++i) {
    int j = j0 + i;
    acc += (float)(j + 1) * hgs[i] * kbase[(size_t)j * PN_PROJ];
    float t = (float)(j + 1);
    kbase[(size_t)j * PN_PROJ] = acc / (t * t);
  }
}

// ---------------------------------------------------------------------------
// Flash attention fp32 (unchanged math), output stored as bf16 in (b,s,h*d).
// ---------------------------------------------------------------------------
__global__ __launch_bounds__(256) void attn_f32(const float* __restrict__ proj,
                                                __hip_bfloat16* __restrict__ O) {
  const int qt = blockIdx.x & 63;
  const int bh = blockIdx.x >> 6;
  const int h = bh & (PH - 1), b = bh >> 4;
  const int tid = threadIdx.x;
  const int tx = tid & 31, ty = tid >> 5;
  const int q0 = qt * 32;

  __shared__ float Qs[32][136];
  __shared__ float Ks[32][132];
  __shared__ float Vs[32][132];
  __shared__ float Ps[32][33];

  const float* base = proj + (size_t)(b * PS) * PN_PROJ + h * (3 * PD);

#pragma unroll
  for (int i = 0; i < 4; ++i) {
    int l = i * 256 + tid;
    int r = l >> 5, c4 = (l & 31) * 4;
    float4 v = *reinterpret_cast<const float4*>(&base[(size_t)(q0 + r) * PN_PROJ + c4]);
    *reinterpret_cast<float4*>(&Qs[r][c4]) = v;
  }

  float m_r[4], l_r[4], o_acc[4][4];
#pragma unroll
  for (int i = 0; i < 4; ++i) {
    m_r[i] = -INFINITY; l_r[i] = 0.f;
#pragma unroll
    for (int j = 0; j < 4; ++j) o_acc[i][j] = 0.f;
  }
  const float scale = 1.0f / sqrtf((float)PE);

  for (int kt = 0; kt <= qt; ++kt) {
    __syncthreads();
#pragma unroll
    for (int i = 0; i < 4; ++i) {
      int l = i * 256 + tid;
      int r = l >> 5, c4 = (l & 31) * 4;
      const float* rowp = &base[(size_t)(kt * 32 + r) * PN_PROJ];
      *reinterpret_cast<float4*>(&Ks[r][c4]) = *reinterpret_cast<const float4*>(&rowp[PD + c4]);
      *reinterpret_cast<float4*>(&Vs[r][c4]) = *reinterpret_cast<const float4*>(&rowp[2 * PD + c4]);
    }
    __syncthreads();

    float sv[4] = {0.f, 0.f, 0.f, 0.f};
#pragma unroll 4
    for (int k4 = 0; k4 < 128; k4 += 4) {
      float4 kv = *reinterpret_cast<const float4*>(&Ks[tx][k4]);
#pragma unroll
      for (int i = 0; i < 4; ++i) {
        float4 qv = *reinterpret_cast<const float4*>(&Qs[ty * 4 + i][k4]);
        sv[i] += qv.x * kv.x + qv.y * kv.y + qv.z * kv.z + qv.w * kv.w;
      }
    }

#pragma unroll
    for (int i = 0; i < 4; ++i) {
      int r = ty * 4 + i;
      float s = sv[i] * scale;
      if (kt == qt && tx > r) s = -INFINITY;
      float mloc = s;
      for (int off = 16; off > 0; off >>= 1) mloc = fmaxf(mloc, __shfl_xor(mloc, off, 64));
      float mnew = fmaxf(m_r[i], mloc);
      float alpha = expf(m_r[i] - mnew);
      float p = expf(s - mnew);
      float lsum = p;
      for (int off = 16; off > 0; off >>= 1) lsum += __shfl_xor(lsum, off, 64);
      l_r[i] = l_r[i] * alpha + lsum;
      m_r[i] = mnew;
      Ps[r][tx] = p;
#pragma unroll
      for (int j = 0; j < 4; ++j) o_acc[i][j] *= alpha;
    }
    __syncthreads();

#pragma unroll 4
    for (int c = 0; c < 32; ++c) {
      float4 vv = *reinterpret_cast<const float4*>(&Vs[c][tx * 4]);
#pragma unroll
      for (int i = 0; i < 4; ++i) {
        float p = Ps[ty * 4 + i][c];
        o_acc[i][0] += p * vv.x; o_acc[i][1] += p * vv.y;
        o_acc[i][2] += p * vv.z; o_acc[i][3] += p * vv.w;
      }
    }
  }

#pragma unroll
  for (int i = 0; i < 4; ++i) {
    int r = ty * 4 + i;
    float inv = 1.0f / l_r[i];
    union { __hip_bfloat16 hh[4]; uint2 u; } pk;
    pk.hh[0] = __float2bfloat16(o_acc[i][0] * inv);
    pk.hh[1] = __float2bfloat16(o_acc[i][1] * inv);
    pk.hh[2] = __float2bfloat16(o_acc[i][2] * inv);
    pk.hh[3] = __float2bfloat16(o_acc[i][3] * inv);
    *(uint2*)&O[(size_t)(b * PS + q0 + r) * PE + h * PD + tx * 4] = pk.u;
  }
}

// ---------------------------------------------------------------------------
extern "C" void kernel_launch(void* const* d_in, const int* in_sizes, int n_in,
                              void* d_out, int out_size, void* d_ws, size_t ws_size,
                              hipStream_t stream) {
  const float* x     = (const float*)d_in[0];   // (B,S,E)
  const float* Wqkvh = (const float*)d_in[1];   // (E, 3E+H)
  const float* Wout  = (const float*)d_in[2];   // (E, E)
  float* out = (float*)d_out;                   // (B,S,E) fp32

  // workspace layout (bytes)
  char* wsb = (char*)d_ws;
  float* proj = (float*)wsb;                                   // 100,925,440 B
  wsb += (size_t)PM * PN_PROJ * 4;
  __hip_bfloat16* xb = (__hip_bfloat16*)wsb;                   // 16,777,216 B (reused as Ob)
  wsb += (size_t)PM * PE * 2;
  __hip_bfloat16* Wq_t = (__hip_bfloat16*)wsb;                 // 25,165,824 B
  wsb += (size_t)PQKV * PE * 2;
  __hip_bfloat16* Wout_t = (__hip_bfloat16*)wsb;               // 8,388,608 B
  wsb += (size_t)PE * PE * 2;
  float* hgbuf = (float*)wsb;                                  // 262,144 B
  wsb += (size_t)PB * PH * PS * 4;
  float* csum = (float*)wsb;                                   // 262,144 B

  // 0) casts / transposes
  cast_f32_bf16<<<(PM * PE / 4 + 255) / 256, 256, 0, stream>>>(x, xb, PM * PE / 4);
  transpose_cast<<<dim3(PQKV / 32, PE / 32), 256, 0, stream>>>(Wqkvh, Wq_t, PN_PROJ, PE, 0);
  transpose_cast<<<dim3(PE / 32, PE / 32), 256, 0, stream>>>(Wout, Wout_t, PE, PE, 0);

  // 1) proj[:, 0:6144] = x @ W_qkvh[:, 0:6144]  (bf16 MFMA)
  gemm_bf16_bt<<<dim3(PQKV / 128, PM / 128), 256, 0, stream>>>(xb, Wq_t, proj, PE, PN_PROJ);

  // 2) gate head (fp32 from x) + chunked causal weighted cumsum (in place)
  hg_from_x<<<PM, 256, 0, stream>>>(x, Wqkvh, hgbuf);
  kc_pass1<<<PB * PH * 16, 128, 0, stream>>>(proj, hgbuf, csum);
  kc_pass2<<<PB * PH * 16, 128, 0, stream>>>(proj, hgbuf, csum);

  // 3) flash attention -> bf16 output in (b,s,h*d) layout (overlays xb)
  __hip_bfloat16* Ob = xb;
  attn_f32<<<PB * PH * (PS / 32), 256, 0, stream>>>(proj, Ob);

  // 4) out = Oattn @ W_out  (bf16 MFMA, fp32 out)
  gemm_bf16_bt<<<dim3(PE / 128, PM / 128), 256, 0, stream>>>(Ob, Wout_t, out, PE, PE);
}

// Round 4
// 471.028 us; speedup vs baseline: 7.0763x; 3.6207x over previous
//
#include <hip/hip_runtime.h>
#include <hip/hip_bf16.h>
#include <math.h>

// Problem constants: B=2, S=2048, E=2048, HEADS=16, d=128
#define PB 2
#define PS 2048
#define PE 2048
#define PH 16
#define PD 128
#define PN_PROJ 6160   // 3*E + HEADS (fp32 weight layout)
#define PM 4096        // B*S
#define PQKV 6144      // 3*E — bf16 proj row length

typedef __attribute__((ext_vector_type(8))) short bf16x8;
typedef __attribute__((ext_vector_type(4))) float f32x4;

__device__ __forceinline__ void gload_lds16(const void* g, void* l) {
  __builtin_amdgcn_global_load_lds((const __attribute__((address_space(1))) void*)g,
                                   (__attribute__((address_space(3))) void*)l, 16, 0, 0);
}

// ---------------------------------------------------------------------------
// bf16 MFMA GEMM (m97 structure): C[M,N] = A[M,K](bf16 rm) @ Bt[N,K](bf16 rm).
// 128x128 tile, BK=32, 4 waves (2x2 of 64x64), 4x4 frags of 16x16x32.
// OutT = float or __hip_bfloat16.
// ---------------------------------------------------------------------------
template <typename OutT>
__global__ __launch_bounds__(256) void gemm_bf16_bt(
    const __hip_bfloat16* __restrict__ A, const __hip_bfloat16* __restrict__ Bt,
    OutT* __restrict__ C, int K, int ldc) {
  __shared__ __align__(16) __hip_bfloat16 As[128 * 32];
  __shared__ __align__(16) __hip_bfloat16 Bs[128 * 32];
  const int tid = threadIdx.x;
  const int wave = tid >> 6, lane = tid & 63;
  const int wr = wave >> 1, wc = wave & 1;
  const int fr = lane & 15, fq = lane >> 4;
  const int mBase = blockIdx.y * 128, nBase = blockIdx.x * 128;
  const int rSeg = lane >> 2;
  const int k8 = (lane & 3) * 8;

  f32x4 acc[4][4];
#pragma unroll
  for (int m = 0; m < 4; ++m)
#pragma unroll
    for (int n = 0; n < 4; ++n) acc[m][n] = (f32x4){0.f, 0.f, 0.f, 0.f};

  for (int kt = 0; kt < K; kt += 32) {
    __syncthreads();
#pragma unroll
    for (int i = 0; i < 2; ++i) {
      int seg = i * 4 + wave;
      int row = seg * 16 + rSeg;
      gload_lds16(&A[(size_t)(mBase + row) * K + kt + k8], &As[seg * 512]);
      gload_lds16(&Bt[(size_t)(nBase + row) * K + kt + k8], &Bs[seg * 512]);
    }
    __syncthreads();

    bf16x8 av[4], bv[4];
#pragma unroll
    for (int m = 0; m < 4; ++m)
      av[m] = *(const bf16x8*)&As[(wr * 64 + m * 16 + fr) * 32 + fq * 8];
#pragma unroll
    for (int n = 0; n < 4; ++n)
      bv[n] = *(const bf16x8*)&Bs[(wc * 64 + n * 16 + fr) * 32 + fq * 8];
#pragma unroll
    for (int m = 0; m < 4; ++m)
#pragma unroll
      for (int n = 0; n < 4; ++n)
        acc[m][n] = __builtin_amdgcn_mfma_f32_16x16x32_bf16(av[m], bv[n], acc[m][n], 0, 0, 0);
  }

#pragma unroll
  for (int m = 0; m < 4; ++m) {
#pragma unroll
    for (int n = 0; n < 4; ++n) {
      int row0 = mBase + wr * 64 + m * 16 + fq * 4;
      int col = nBase + wc * 64 + n * 16 + fr;
#pragma unroll
      for (int j = 0; j < 4; ++j) {
        if constexpr (__is_same(OutT, float))
          C[(size_t)(row0 + j) * ldc + col] = acc[m][n][j];
        else
          C[(size_t)(row0 + j) * ldc + col] = __float2bfloat16(acc[m][n][j]);
      }
    }
  }
}

// ---------------------------------------------------------------------------
__global__ __launch_bounds__(256) void cast_f32_bf16(const float* __restrict__ in,
                                                     __hip_bfloat16* __restrict__ out,
                                                     int n4) {
  int i = blockIdx.x * 256 + threadIdx.x;
  if (i >= n4) return;
  float4 v = ((const float4*)in)[i];
  union { __hip_bfloat16 h[4]; uint2 u; } pk;
  pk.h[0] = __float2bfloat16(v.x); pk.h[1] = __float2bfloat16(v.y);
  pk.h[2] = __float2bfloat16(v.z); pk.h[3] = __float2bfloat16(v.w);
  ((uint2*)out)[i] = pk.u;
}

// ---------------------------------------------------------------------------
__global__ __launch_bounds__(256) void transpose_cast(const float* __restrict__ W,
                                                      __hip_bfloat16* __restrict__ Wt,
                                                      int ldw, int ldt, int nOff) {
  __shared__ float t[32][33];
  int nb = blockIdx.x * 32, kb = blockIdx.y * 32;
  int tx = threadIdx.x & 31, ty = threadIdx.x >> 5;
#pragma unroll
  for (int i = 0; i < 4; ++i) {
    int k = ty + i * 8;
    t[k][tx] = W[(size_t)(kb + k) * ldw + nOff + nb + tx];
  }
  __syncthreads();
#pragma unroll
  for (int i = 0; i < 4; ++i) {
    int n = ty + i * 8;
    Wt[(size_t)(nb + n) * ldt + kb + tx] = __float2bfloat16(t[tx][n]);
  }
}

// ---------------------------------------------------------------------------
// Gate head from x (fp32): hgbuf[(b*H+h)*S+s] = tanh(x[bs,:] . W[:,3E+h])
// ---------------------------------------------------------------------------
__global__ __launch_bounds__(256) void hg_from_x(const float* __restrict__ x,
                                                 const float* __restrict__ W,
                                                 float* __restrict__ hgbuf) {
  int bs = blockIdx.x;
  int b = bs >> 11, s = bs & (PS - 1);
  __shared__ float xs[PE];
  __shared__ float red[16][17];
  const float* xr = x + (size_t)bs * PE;
  for (int i = threadIdx.x; i < PE / 4; i += 256)
    *(float4*)&xs[i * 4] = ((const float4*)xr)[i];
  __syncthreads();
  int h = threadIdx.x & 15, part = threadIdx.x >> 4;
  float acc = 0.f;
  for (int k = part * 128; k < part * 128 + 128; ++k)
    acc += xs[k] * W[(size_t)k * PN_PROJ + 3 * PE + h];
  red[part][h] = acc;
  __syncthreads();
  if (threadIdx.x < 16) {
    float sm = 0.f;
#pragma unroll
    for (int p = 0; p < 16; ++p) sm += red[p][threadIdx.x];
    hgbuf[(size_t)(b * PH + threadIdx.x) * PS + s] = tanhf(sm);
  }
}

// ---------------------------------------------------------------------------
// Kc scan on bf16 proj (fp32 accumulation). proj: [4096][6144] bf16,
// K slot = cols h*384+128 .. +255. Kc written back as bf16.
// ---------------------------------------------------------------------------
__global__ __launch_bounds__(128) void kc_pass1(const __hip_bfloat16* __restrict__ proj,
                                                const float* __restrict__ hgbuf,
                                                float* __restrict__ csum) {
  int c = blockIdx.x & 15, bh = blockIdx.x >> 4;
  int h = bh & (PH - 1), b = bh >> 4;
  int d = threadIdx.x;
  __shared__ float hgs[128];
  hgs[d] = hgbuf[bh * PS + c * 128 + d];
  __syncthreads();
  const __hip_bfloat16* kbase = proj + (size_t)(b * PS) * PQKV + h * 384 + 128 + d;
  float acc = 0.f;
  int j0 = c * 128;
  for (int i = 0; i < 128; ++i) {
    int j = j0 + i;
    acc += (float)(j + 1) * hgs[i] * __bfloat162float(kbase[(size_t)j * PQKV]);
  }
  csum[blockIdx.x * 128 + d] = acc;
}

__global__ __launch_bounds__(128) void kc_pass2(__hip_bfloat16* __restrict__ proj,
                                                const float* __restrict__ hgbuf,
                                                const float* __restrict__ csum) {
  int c = blockIdx.x & 15, bh = blockIdx.x >> 4;
  int h = bh & (PH - 1), b = bh >> 4;
  int d = threadIdx.x;
  __shared__ float hgs[128];
  hgs[d] = hgbuf[bh * PS + c * 128 + d];
  __syncthreads();
  float acc = 0.f;
  for (int cc = 0; cc < c; ++cc) acc += csum[(bh * 16 + cc) * 128 + d];
  __hip_bfloat16* kbase = proj + (size_t)(b * PS) * PQKV + h * 384 + 128 + d;
  int j0 = c * 128;
  for (int i = 0; i < 128; ++i) {
    int j = j0 + i;
    acc += (float)(j + 1) * hgs[i] * __bfloat162float(kbase[(size_t)j * PQKV]);
    float t = (float)(j + 1);
    kbase[(size_t)j * PQKV] = __float2bfloat16(acc / (t * t));
  }
}

// ---------------------------------------------------------------------------
// V^T pack: Vtp[bh][d][s] = proj V slot. One block per (bh, 64-row s-chunk).
// ---------------------------------------------------------------------------
__global__ __launch_bounds__(256) void vt_pack(const __hip_bfloat16* __restrict__ proj,
                                               __hip_bfloat16* __restrict__ Vtp) {
  int sc = blockIdx.x & 31, bh = blockIdx.x >> 5;
  int b = bh >> 4, h = bh & 15;
  int s0 = sc * 64;
  int tid = threadIdx.x;
  __shared__ __align__(16) __hip_bfloat16 Vlds[64][136];
  const __hip_bfloat16* src = proj + (size_t)(b * PS + s0) * PQKV + h * 384 + 256;
#pragma unroll
  for (int it = 0; it < 4; ++it) {
    int i = it * 256 + tid;
    int row = i >> 4, ch = i & 15;
    *(bf16x8*)&Vlds[row][ch * 8] = *(const bf16x8*)&src[(size_t)row * PQKV + ch * 8];
  }
  __syncthreads();
  int d = tid >> 1, half = tid & 1;
  __hip_bfloat16* dst = Vtp + ((size_t)bh * 128 + d) * PS + s0 + half * 32;
#pragma unroll
  for (int c8 = 0; c8 < 8; ++c8) {
    union { __hip_bfloat16 h4[4]; uint2 u; } pk;
#pragma unroll
    for (int k = 0; k < 4; ++k) pk.h4[k] = Vlds[half * 32 + c8 * 4 + k][d];
    *(uint2*)&dst[c8 * 4] = pk.u;
  }
}

// ---------------------------------------------------------------------------
// MFMA flash attention. Block: 256 thr = 4 waves; QBLK=64 (16 q-rows/wave),
// KVBLK=64. QK^T and PV via mfma_f32_16x16x32_bf16. Online softmax via
// 16-lane shfl_xor reduce. Padded LDS (stride%32dw==4) -> ~2-way conflicts.
// Output O[b*S+s][h*128+d] bf16, staged through LDS for coalesced stores.
// ---------------------------------------------------------------------------
__global__ __launch_bounds__(256) void attn_mfma(const __hip_bfloat16* __restrict__ proj,
                                                 const __hip_bfloat16* __restrict__ Vtp,
                                                 __hip_bfloat16* __restrict__ O) {
  // XCD-aware bijective swizzle (grid 1024 % 8 == 0): 128 consecutive logical
  // blocks (4 heads) per XCD -> K/V stay in one L2.
  const int lbid = (blockIdx.x & 7) * 128 + (blockIdx.x >> 3);
  const int qt = lbid & 31, bh = lbid >> 5;
  const int b = bh >> 4, h = bh & 15;
  const int tid = threadIdx.x;
  const int w = tid >> 6, lane = tid & 63;
  const int fr = lane & 15, fq = lane >> 4;
  const int q0 = qt * 64;

  __shared__ __align__(16) __hip_bfloat16 Ks[64 * 136];   // [k-row][d], pad 8
  __shared__ __align__(16) __hip_bfloat16 Vts[128 * 72];  // [d-row][k], pad 8
  __shared__ __align__(16) __hip_bfloat16 Ps[4][16 * 72]; // per wave [q-row][k]

  // Q fragments (held in registers for the whole kernel)
  const __hip_bfloat16* qrow = proj + (size_t)(b * PS + q0 + w * 16 + fr) * PQKV + h * 384;
  bf16x8 qf[4];
#pragma unroll
  for (int kk = 0; kk < 4; ++kk) qf[kk] = *(const bf16x8*)&qrow[kk * 32 + fq * 8];

  f32x4 oacc[8];
#pragma unroll
  for (int nd = 0; nd < 8; ++nd) oacc[nd] = (f32x4){0.f, 0.f, 0.f, 0.f};
  float m_j[4], l_j[4];
#pragma unroll
  for (int j = 0; j < 4; ++j) { m_j[j] = -__builtin_inff(); l_j[j] = 0.f; }
  const float scale = 0.022097086912079608f;  // 1/sqrt(2048)

  const __hip_bfloat16* kb0 = proj + (size_t)(b * PS) * PQKV + h * 384 + 128;
  const __hip_bfloat16* vb0 = Vtp + (size_t)bh * 128 * PS;

  for (int kt = 0; kt <= qt; ++kt) {
    __syncthreads();  // prev iter's PV done with Vts/Ps
    // stage K tile [64][128]
    const __hip_bfloat16* kb = kb0 + (size_t)(kt * 64) * PQKV;
#pragma unroll
    for (int it = 0; it < 4; ++it) {
      int i = it * 256 + tid;
      int row = i >> 4, ch = i & 15;
      *(bf16x8*)&Ks[row * 136 + ch * 8] = *(const bf16x8*)&kb[(size_t)row * PQKV + ch * 8];
    }
    // stage V^T tile [128][64]
    const __hip_bfloat16* vb = vb0 + kt * 64;
#pragma unroll
    for (int it = 0; it < 4; ++it) {
      int i = it * 256 + tid;
      int row = i >> 3, ch = i & 7;
      *(bf16x8*)&Vts[row * 72 + ch * 8] = *(const bf16x8*)&vb[(size_t)row * PS + ch * 8];
    }
    __syncthreads();

    // QK^T: sacc[n] = Q(16x128) . K^T -> 16x64
    f32x4 sacc[4];
#pragma unroll
    for (int n = 0; n < 4; ++n) sacc[n] = (f32x4){0.f, 0.f, 0.f, 0.f};
#pragma unroll
    for (int kk = 0; kk < 4; ++kk) {
#pragma unroll
      for (int n = 0; n < 4; ++n) {
        bf16x8 bv = *(const bf16x8*)&Ks[(n * 16 + fr) * 136 + kk * 32 + fq * 8];
        sacc[n] = __builtin_amdgcn_mfma_f32_16x16x32_bf16(qf[kk], bv, sacc[n], 0, 0, 0);
      }
    }

    // online softmax; lane holds rows (w*16 + fq*4 + j), cols (n*16 + fr)
    float sv[4][4];
#pragma unroll
    for (int n = 0; n < 4; ++n)
#pragma unroll
      for (int j = 0; j < 4; ++j) {
        float s = sacc[n][j] * scale;
        if (kt == qt && (n * 16 + fr) > (w * 16 + fq * 4 + j)) s = -__builtin_inff();
        sv[n][j] = s;
      }
#pragma unroll
    for (int j = 0; j < 4; ++j) {
      float mloc = fmaxf(fmaxf(sv[0][j], sv[1][j]), fmaxf(sv[2][j], sv[3][j]));
#pragma unroll
      for (int off = 1; off < 16; off <<= 1) mloc = fmaxf(mloc, __shfl_xor(mloc, off, 64));
      float mn = fmaxf(m_j[j], mloc);
      float alpha = expf(m_j[j] - mn);
      m_j[j] = mn;
      float ls = 0.f;
#pragma unroll
      for (int n = 0; n < 4; ++n) {
        float p = expf(sv[n][j] - mn);
        sv[n][j] = p;
        ls += p;
      }
#pragma unroll
      for (int off = 1; off < 16; off <<= 1) ls += __shfl_xor(ls, off, 64);
      l_j[j] = l_j[j] * alpha + ls;
#pragma unroll
      for (int nd = 0; nd < 8; ++nd) oacc[nd][j] *= alpha;
    }
    // write P tile (bf16) for this wave
#pragma unroll
    for (int n = 0; n < 4; ++n)
#pragma unroll
      for (int j = 0; j < 4; ++j)
        Ps[w][(fq * 4 + j) * 72 + n * 16 + fr] = __float2bfloat16(sv[n][j]);
    __syncthreads();

    // PV: O(16x128) += P(16x64) . V(64x128), B-frag from V^T tile
#pragma unroll
    for (int kk2 = 0; kk2 < 2; ++kk2) {
      bf16x8 pa = *(const bf16x8*)&Ps[w][fr * 72 + kk2 * 32 + fq * 8];
#pragma unroll
      for (int nd = 0; nd < 8; ++nd) {
        bf16x8 bv = *(const bf16x8*)&Vts[(nd * 16 + fr) * 72 + kk2 * 32 + fq * 8];
        oacc[nd] = __builtin_amdgcn_mfma_f32_16x16x32_bf16(pa, bv, oacc[nd], 0, 0, 0);
      }
    }
  }

  // epilogue: normalize, stage O in LDS (reuse Ks), coalesced bf16 store.
  // Safe: Ks last read before the P-write barrier of the final tile.
  __hip_bfloat16* Os = Ks;
  float inv[4];
#pragma unroll
  for (int j = 0; j < 4; ++j) inv[j] = 1.0f / l_j[j];
#pragma unroll
  for (int nd = 0; nd < 8; ++nd)
#pragma unroll
    for (int j = 0; j < 4; ++j)
      Os[(w * 16 + fq * 4 + j) * 136 + nd * 16 + fr] = __float2bfloat16(oacc[nd][j] * inv[j]);
  __syncthreads();
#pragma unroll
  for (int it = 0; it < 4; ++it) {
    int i = it * 256 + tid;
    int row = i >> 4, ch = i & 15;
    *(bf16x8*)&O[(size_t)(b * PS + q0 + row) * PE + h * 128 + ch * 8] =
        *(const bf16x8*)&Os[row * 136 + ch * 8];
  }
}

// ---------------------------------------------------------------------------
extern "C" void kernel_launch(void* const* d_in, const int* in_sizes, int n_in,
                              void* d_out, int out_size, void* d_ws, size_t ws_size,
                              hipStream_t stream) {
  const float* x     = (const float*)d_in[0];
  const float* Wqkvh = (const float*)d_in[1];
  const float* Wout  = (const float*)d_in[2];
  float* out = (float*)d_out;

  // workspace layout (~118 MB)
  char* wsb = (char*)d_ws;
  __hip_bfloat16* proj = (__hip_bfloat16*)wsb;          // [4096][6144] bf16: 50.3 MB
  wsb += (size_t)PM * PQKV * 2;
  __hip_bfloat16* xb = (__hip_bfloat16*)wsb;            // 16.8 MB (reused as attn out)
  wsb += (size_t)PM * PE * 2;
  __hip_bfloat16* Wq_t = (__hip_bfloat16*)wsb;          // 25.2 MB
  wsb += (size_t)PQKV * PE * 2;
  __hip_bfloat16* Wout_t = (__hip_bfloat16*)wsb;        // 8.4 MB
  wsb += (size_t)PE * PE * 2;
  __hip_bfloat16* Vtp = (__hip_bfloat16*)wsb;           // [32][128][2048] bf16: 16.8 MB
  wsb += (size_t)PB * PH * PD * PS * 2;
  float* hgbuf = (float*)wsb;                           // 0.26 MB
  wsb += (size_t)PB * PH * PS * 4;
  float* csum = (float*)wsb;                            // 0.26 MB

  // 0) casts / weight transposes
  cast_f32_bf16<<<(PM * PE / 4 + 255) / 256, 256, 0, stream>>>(x, xb, PM * PE / 4);
  transpose_cast<<<dim3(PQKV / 32, PE / 32), 256, 0, stream>>>(Wqkvh, Wq_t, PN_PROJ, PE, 0);
  transpose_cast<<<dim3(PE / 32, PE / 32), 256, 0, stream>>>(Wout, Wout_t, PE, PE, 0);

  // 1) proj = x @ W_qkvh[:, :6144]  (bf16 out)
  gemm_bf16_bt<__hip_bfloat16><<<dim3(PQKV / 128, PM / 128), 256, 0, stream>>>(
      xb, Wq_t, proj, PE, PQKV);

  // 2) gate head (fp32 from x) + causal weighted cumsum (bf16 in place)
  hg_from_x<<<PM, 256, 0, stream>>>(x, Wqkvh, hgbuf);
  kc_pass1<<<PB * PH * 16, 128, 0, stream>>>(proj, hgbuf, csum);
  kc_pass2<<<PB * PH * 16, 128, 0, stream>>>(proj, hgbuf, csum);

  // 3) V^T pack + MFMA flash attention -> xb (as O, layout (b,s,h*d))
  vt_pack<<<PB * PH * 32, 256, 0, stream>>>(proj, Vtp);
  __hip_bfloat16* Ob = xb;
  attn_mfma<<<PB * PH * (PS / 64), 256, 0, stream>>>(proj, Vtp, Ob);

  // 4) out = Oattn @ W_out (fp32 out)
  gemm_bf16_bt<float><<<dim3(PE / 128, PM / 128), 256, 0, stream>>>(
      Ob, Wout_t, out, PE, PE);
}

// Round 5
// 420.845 us; speedup vs baseline: 7.9201x; 1.1192x over previous
//
#include <hip/hip_runtime.h>
#include <hip/hip_bf16.h>
#include <math.h>

// Problem constants: B=2, S=2048, E=2048, HEADS=16, d=128
#define PB 2
#define PS 2048
#define PE 2048
#define PH 16
#define PD 128
#define PN_PROJ 6160   // 3*E + HEADS (fp32 weight layout)
#define PM 4096        // B*S
#define PQKV 6144      // 3*E — bf16 proj row length

typedef __attribute__((ext_vector_type(8))) short bf16x8;
typedef __attribute__((ext_vector_type(4))) float f32x4;

__device__ __forceinline__ void gload_lds16(const void* g, void* l) {
  __builtin_amdgcn_global_load_lds((const __attribute__((address_space(1))) void*)g,
                                   (__attribute__((address_space(3))) void*)l, 16, 0, 0);
}

// ---------------------------------------------------------------------------
// bf16 MFMA GEMM (m97 structure): C[M,N] = A[M,K](bf16 rm) @ Bt[N,K](bf16 rm).
// ---------------------------------------------------------------------------
template <typename OutT>
__global__ __launch_bounds__(256) void gemm_bf16_bt(
    const __hip_bfloat16* __restrict__ A, const __hip_bfloat16* __restrict__ Bt,
    OutT* __restrict__ C, int K, int ldc) {
  __shared__ __align__(16) __hip_bfloat16 As[128 * 32];
  __shared__ __align__(16) __hip_bfloat16 Bs[128 * 32];
  const int tid = threadIdx.x;
  const int wave = tid >> 6, lane = tid & 63;
  const int wr = wave >> 1, wc = wave & 1;
  const int fr = lane & 15, fq = lane >> 4;
  const int mBase = blockIdx.y * 128, nBase = blockIdx.x * 128;
  const int rSeg = lane >> 2;
  const int k8 = (lane & 3) * 8;

  f32x4 acc[4][4];
#pragma unroll
  for (int m = 0; m < 4; ++m)
#pragma unroll
    for (int n = 0; n < 4; ++n) acc[m][n] = (f32x4){0.f, 0.f, 0.f, 0.f};

  for (int kt = 0; kt < K; kt += 32) {
    __syncthreads();
#pragma unroll
    for (int i = 0; i < 2; ++i) {
      int seg = i * 4 + wave;
      int row = seg * 16 + rSeg;
      gload_lds16(&A[(size_t)(mBase + row) * K + kt + k8], &As[seg * 512]);
      gload_lds16(&Bt[(size_t)(nBase + row) * K + kt + k8], &Bs[seg * 512]);
    }
    __syncthreads();

    bf16x8 av[4], bv[4];
#pragma unroll
    for (int m = 0; m < 4; ++m)
      av[m] = *(const bf16x8*)&As[(wr * 64 + m * 16 + fr) * 32 + fq * 8];
#pragma unroll
    for (int n = 0; n < 4; ++n)
      bv[n] = *(const bf16x8*)&Bs[(wc * 64 + n * 16 + fr) * 32 + fq * 8];
#pragma unroll
    for (int m = 0; m < 4; ++m)
#pragma unroll
      for (int n = 0; n < 4; ++n)
        acc[m][n] = __builtin_amdgcn_mfma_f32_16x16x32_bf16(av[m], bv[n], acc[m][n], 0, 0, 0);
  }

#pragma unroll
  for (int m = 0; m < 4; ++m) {
#pragma unroll
    for (int n = 0; n < 4; ++n) {
      int row0 = mBase + wr * 64 + m * 16 + fq * 4;
      int col = nBase + wc * 64 + n * 16 + fr;
#pragma unroll
      for (int j = 0; j < 4; ++j) {
        if constexpr (__is_same(OutT, float))
          C[(size_t)(row0 + j) * ldc + col] = acc[m][n][j];
        else
          C[(size_t)(row0 + j) * ldc + col] = __float2bfloat16(acc[m][n][j]);
      }
    }
  }
}

// ---------------------------------------------------------------------------
__global__ __launch_bounds__(256) void cast_f32_bf16(const float* __restrict__ in,
                                                     __hip_bfloat16* __restrict__ out,
                                                     int n4) {
  int i = blockIdx.x * 256 + threadIdx.x;
  if (i >= n4) return;
  float4 v = ((const float4*)in)[i];
  union { __hip_bfloat16 h[4]; uint2 u; } pk;
  pk.h[0] = __float2bfloat16(v.x); pk.h[1] = __float2bfloat16(v.y);
  pk.h[2] = __float2bfloat16(v.z); pk.h[3] = __float2bfloat16(v.w);
  ((uint2*)out)[i] = pk.u;
}

// ---------------------------------------------------------------------------
__global__ __launch_bounds__(256) void transpose_cast(const float* __restrict__ W,
                                                      __hip_bfloat16* __restrict__ Wt,
                                                      int ldw, int ldt, int nOff) {
  __shared__ float t[32][33];
  int nb = blockIdx.x * 32, kb = blockIdx.y * 32;
  int tx = threadIdx.x & 31, ty = threadIdx.x >> 5;
#pragma unroll
  for (int i = 0; i < 4; ++i) {
    int k = ty + i * 8;
    t[k][tx] = W[(size_t)(kb + k) * ldw + nOff + nb + tx];
  }
  __syncthreads();
#pragma unroll
  for (int i = 0; i < 4; ++i) {
    int n = ty + i * 8;
    Wt[(size_t)(nb + n) * ldt + kb + tx] = __float2bfloat16(t[tx][n]);
  }
}

// ---------------------------------------------------------------------------
// Gate head from x (fp32): hgbuf[(b*H+h)*S+s] = tanh(x[bs,:] . W[:,3E+h])
// ---------------------------------------------------------------------------
__global__ __launch_bounds__(256) void hg_from_x(const float* __restrict__ x,
                                                 const float* __restrict__ W,
                                                 float* __restrict__ hgbuf) {
  int bs = blockIdx.x;
  int b = bs >> 11, s = bs & (PS - 1);
  __shared__ float xs[PE];
  __shared__ float red[16][17];
  const float* xr = x + (size_t)bs * PE;
  for (int i = threadIdx.x; i < PE / 4; i += 256)
    *(float4*)&xs[i * 4] = ((const float4*)xr)[i];
  __syncthreads();
  int h = threadIdx.x & 15, part = threadIdx.x >> 4;
  float acc = 0.f;
  for (int k = part * 128; k < part * 128 + 128; ++k)
    acc += xs[k] * W[(size_t)k * PN_PROJ + 3 * PE + h];
  red[part][h] = acc;
  __syncthreads();
  if (threadIdx.x < 16) {
    float sm = 0.f;
#pragma unroll
    for (int p = 0; p < 16; ++p) sm += red[p][threadIdx.x];
    hgbuf[(size_t)(b * PH + threadIdx.x) * PS + s] = tanhf(sm);
  }
}

// ---------------------------------------------------------------------------
// Kc scan on bf16 proj (fp32 accumulation). Kc written back as bf16,
// PRE-SCALED by 1/sqrt(E) (folded out of the attention kernel).
// ---------------------------------------------------------------------------
#define KC_SCALE 0.022097086912079608f  // 1/sqrt(2048)

__global__ __launch_bounds__(128) void kc_pass1(const __hip_bfloat16* __restrict__ proj,
                                                const float* __restrict__ hgbuf,
                                                float* __restrict__ csum) {
  int c = blockIdx.x & 15, bh = blockIdx.x >> 4;
  int h = bh & (PH - 1), b = bh >> 4;
  int d = threadIdx.x;
  __shared__ float hgs[128];
  hgs[d] = hgbuf[bh * PS + c * 128 + d];
  __syncthreads();
  const __hip_bfloat16* kbase = proj + (size_t)(b * PS) * PQKV + h * 384 + 128 + d;
  float acc = 0.f;
  int j0 = c * 128;
  for (int i = 0; i < 128; ++i) {
    int j = j0 + i;
    acc += (float)(j + 1) * hgs[i] * __bfloat162float(kbase[(size_t)j * PQKV]);
  }
  csum[blockIdx.x * 128 + d] = acc;
}

__global__ __launch_bounds__(128) void kc_pass2(__hip_bfloat16* __restrict__ proj,
                                                const float* __restrict__ hgbuf,
                                                const float* __restrict__ csum) {
  int c = blockIdx.x & 15, bh = blockIdx.x >> 4;
  int h = bh & (PH - 1), b = bh >> 4;
  int d = threadIdx.x;
  __shared__ float hgs[128];
  hgs[d] = hgbuf[bh * PS + c * 128 + d];
  __syncthreads();
  float acc = 0.f;
  for (int cc = 0; cc < c; ++cc) acc += csum[(bh * 16 + cc) * 128 + d];
  __hip_bfloat16* kbase = proj + (size_t)(b * PS) * PQKV + h * 384 + 128 + d;
  int j0 = c * 128;
  for (int i = 0; i < 128; ++i) {
    int j = j0 + i;
    acc += (float)(j + 1) * hgs[i] * __bfloat162float(kbase[(size_t)j * PQKV]);
    float t = (float)(j + 1);
    kbase[(size_t)j * PQKV] = __float2bfloat16(acc / (t * t) * KC_SCALE);
  }
}

// ---------------------------------------------------------------------------
// V^T pack: Vtp[bh][d][s]
// ---------------------------------------------------------------------------
__global__ __launch_bounds__(256) void vt_pack(const __hip_bfloat16* __restrict__ proj,
                                               __hip_bfloat16* __restrict__ Vtp) {
  int sc = blockIdx.x & 31, bh = blockIdx.x >> 5;
  int b = bh >> 4, h = bh & 15;
  int s0 = sc * 64;
  int tid = threadIdx.x;
  __shared__ __align__(16) __hip_bfloat16 Vlds[64][136];
  const __hip_bfloat16* src = proj + (size_t)(b * PS + s0) * PQKV + h * 384 + 256;
#pragma unroll
  for (int it = 0; it < 4; ++it) {
    int i = it * 256 + tid;
    int row = i >> 4, ch = i & 15;
    *(bf16x8*)&Vlds[row][ch * 8] = *(const bf16x8*)&src[(size_t)row * PQKV + ch * 8];
  }
  __syncthreads();
  int d = tid >> 1, half = tid & 1;
  __hip_bfloat16* dst = Vtp + ((size_t)bh * 128 + d) * PS + s0 + half * 32;
#pragma unroll
  for (int c8 = 0; c8 < 8; ++c8) {
    union { __hip_bfloat16 h4[4]; uint2 u; } pk;
#pragma unroll
    for (int k = 0; k < 4; ++k) pk.h4[k] = Vlds[half * 32 + c8 * 4 + k][d];
    *(uint2*)&dst[c8 * 4] = pk.u;
  }
}

// ---------------------------------------------------------------------------
// MFMA flash attention v2.
// Block: 256 thr = 4 waves; QBLK=128 (32 q-rows/wave in 2 rowgroups), KVBLK=64.
// Swapped QK^T (mfma(K,Q) -> S[k][q]): lane owns one q-row per rowgroup;
// softmax reduce = 2 shfl_xor; P written as b64; defer-max (THR=8).
// K/V LDS: unpadded pow2 rows + 16B-chunk XOR (row&7) swizzle, staged with
// global_load_lds from pre-swizzled global addresses (linear LDS dest).
// Kc is pre-scaled by 1/sqrt(E) in kc_pass2.
// ---------------------------------------------------------------------------
__global__ __launch_bounds__(256) void attn_mfma(const __hip_bfloat16* __restrict__ proj,
                                                 const __hip_bfloat16* __restrict__ Vtp,
                                                 __hip_bfloat16* __restrict__ O) {
  // bijective XCD chunking: 512 blocks -> 64 consecutive lbid per XCD
  const int lbid = (blockIdx.x & 7) * 64 + (blockIdx.x >> 3);
  const int bh = lbid >> 4, qt = lbid & 15;
  const int b = bh >> 4, h = bh & 15;
  const int tid = threadIdx.x;
  const int w = tid >> 6, lane = tid & 63;
  const int fq = lane >> 4, fr = lane & 15;
  const int q0 = qt * 128;
  const int nt = (qt + 1) * 2;
  const int qw = q0 + w * 32;  // wave's first q row

  // LDS: Ks 16K | Vts 16K | Ps 18K  (epilogue overlays Os 34.8K on the front)
  __shared__ __align__(16) char smem[51200];
  __hip_bfloat16* Ks  = (__hip_bfloat16*)smem;              // [64][128]
  __hip_bfloat16* Vts = (__hip_bfloat16*)(smem + 16384);    // [128][64]
  __hip_bfloat16* Psw = (__hip_bfloat16*)(smem + 32768) + w * 32 * 72;  // [32][72]

  // Q fragments: B-side cols = q rows; lane (fq,fr) -> q = qw + r2*16+fr
  const __hip_bfloat16* qbase = proj + (size_t)(b * PS + qw) * PQKV + h * 384;
  bf16x8 qf[2][4];
#pragma unroll
  for (int r2 = 0; r2 < 2; ++r2)
#pragma unroll
    for (int kk = 0; kk < 4; ++kk)
      qf[r2][kk] = *(const bf16x8*)&qbase[(size_t)(r2 * 16 + fr) * PQKV + kk * 32 + fq * 8];

  f32x4 oacc[2][8];
#pragma unroll
  for (int r2 = 0; r2 < 2; ++r2)
#pragma unroll
    for (int nd = 0; nd < 8; ++nd) oacc[r2][nd] = (f32x4){0.f, 0.f, 0.f, 0.f};
  float m_[2] = {-__builtin_inff(), -__builtin_inff()};
  float l_[2] = {0.f, 0.f};

  const __hip_bfloat16* kb0 = proj + (size_t)(b * PS) * PQKV + h * 384 + 128;
  const __hip_bfloat16* vb0 = Vtp + (size_t)bh * 128 * PS;

  const int klr = lane >> 4, kc = lane & 15;  // K staging: 4 rows x 16 chunks
  const int vlr = lane >> 3, vc = lane & 7;   // V staging: 8 rows x 8 chunks

  for (int kt = 0; kt < nt; ++kt) {
    __syncthreads();  // all waves done reading Ks/Vts/(wave-local Ps)
    // stage K tile [64][128]: linear LDS dest, pre-swizzled global source
#pragma unroll
    for (int p = 0; p < 4; ++p) {
      int row = w * 16 + p * 4 + klr;
      int cs = kc ^ (row & 7);
      gload_lds16(kb0 + (size_t)(kt * 64 + row) * PQKV + cs * 8, &Ks[(w * 16 + p * 4) * 128]);
    }
    // stage V^T tile [128][64]
#pragma unroll
    for (int p = 0; p < 4; ++p) {
      int row = w * 32 + p * 8 + vlr;
      int cs = vc ^ (row & 7);
      gload_lds16(vb0 + (size_t)row * PS + kt * 64 + cs * 8, &Vts[(w * 32 + p * 8) * 64]);
    }
    __syncthreads();

    if (kt * 64 > qw + 31) continue;  // tile fully above diagonal for this wave
    const bool diag = (kt * 64 + 63) > qw;

    // QK^T swapped: sacc[r2][n][j] = S[k = kt*64 + n*16+fq*4+j][q = qw + r2*16+fr]
    f32x4 sacc[2][4];
#pragma unroll
    for (int r2 = 0; r2 < 2; ++r2)
#pragma unroll
      for (int n = 0; n < 4; ++n) sacc[r2][n] = (f32x4){0.f, 0.f, 0.f, 0.f};
#pragma unroll
    for (int kk = 0; kk < 4; ++kk) {
#pragma unroll
      for (int n = 0; n < 4; ++n) {
        bf16x8 kf = *(const bf16x8*)&Ks[(n * 16 + fr) * 128 + (((kk * 4 + fq) ^ (fr & 7)) * 8)];
        sacc[0][n] = __builtin_amdgcn_mfma_f32_16x16x32_bf16(kf, qf[0][kk], sacc[0][n], 0, 0, 0);
        sacc[1][n] = __builtin_amdgcn_mfma_f32_16x16x32_bf16(kf, qf[1][kk], sacc[1][n], 0, 0, 0);
      }
    }

    // softmax + P write + PV per rowgroup
#pragma unroll
    for (int r2 = 0; r2 < 2; ++r2) {
      const int qg = qw + r2 * 16 + fr;
      float sv[4][4];
#pragma unroll
      for (int n = 0; n < 4; ++n)
#pragma unroll
        for (int j = 0; j < 4; ++j) {
          float s = sacc[r2][n][j];
          if (diag && (kt * 64 + n * 16 + fq * 4 + j) > qg) s = -__builtin_inff();
          sv[n][j] = s;
        }
      float pmax = sv[0][0];
#pragma unroll
      for (int n = 0; n < 4; ++n)
#pragma unroll
        for (int j = 0; j < 4; ++j) pmax = fmaxf(pmax, sv[n][j]);
      pmax = fmaxf(pmax, __shfl_xor(pmax, 16, 64));
      pmax = fmaxf(pmax, __shfl_xor(pmax, 32, 64));

      const bool nof = __all(pmax <= m_[r2] + 8.f);  // defer-max (T13)
      const float mn = nof ? m_[r2] : fmaxf(m_[r2], pmax);
      float ps = 0.f;
#pragma unroll
      for (int n = 0; n < 4; ++n) {
        union { __hip_bfloat16 hh[4]; uint2 u; } pk;
#pragma unroll
        for (int j = 0; j < 4; ++j) {
          float p = __expf(sv[n][j] - mn);
          ps += p;
          pk.hh[j] = __float2bfloat16(p);
        }
        *(uint2*)&Psw[(r2 * 16 + fr) * 72 + n * 16 + fq * 4] = pk.u;
      }
      ps += __shfl_xor(ps, 16, 64);
      ps += __shfl_xor(ps, 32, 64);

      if (!nof) {
        const float alpha = __expf(m_[r2] - mn);
        l_[r2] = l_[r2] * alpha + ps;
        m_[r2] = mn;
        float a0 = __shfl(alpha, fq * 4 + 0, 64);
        float a1 = __shfl(alpha, fq * 4 + 1, 64);
        float a2 = __shfl(alpha, fq * 4 + 2, 64);
        float a3 = __shfl(alpha, fq * 4 + 3, 64);
#pragma unroll
        for (int nd = 0; nd < 8; ++nd) {
          oacc[r2][nd][0] *= a0; oacc[r2][nd][1] *= a1;
          oacc[r2][nd][2] *= a2; oacc[r2][nd][3] *= a3;
        }
      } else {
        l_[r2] += ps;
      }
    }

    // PV: oacc[r2][nd] += P(16x64) . V(64x128); V-frags reused across r2
#pragma unroll
    for (int kk2 = 0; kk2 < 2; ++kk2) {
      bf16x8 pa0 = *(const bf16x8*)&Psw[(0 * 16 + fr) * 72 + kk2 * 32 + fq * 8];
      bf16x8 pa1 = *(const bf16x8*)&Psw[(1 * 16 + fr) * 72 + kk2 * 32 + fq * 8];
#pragma unroll
      for (int nd = 0; nd < 8; ++nd) {
        bf16x8 vf = *(const bf16x8*)&Vts[(nd * 16 + fr) * 64 + (((kk2 * 4 + fq) ^ (fr & 7)) * 8)];
        oacc[0][nd] = __builtin_amdgcn_mfma_f32_16x16x32_bf16(pa0, vf, oacc[0][nd], 0, 0, 0);
        oacc[1][nd] = __builtin_amdgcn_mfma_f32_16x16x32_bf16(pa1, vf, oacc[1][nd], 0, 0, 0);
      }
    }
  }

  // epilogue: normalize, stage O (bf16) over smem, coalesced store
  float i0 = 1.0f / l_[0], i1 = 1.0f / l_[1];
  float inv4[2][4];
#pragma unroll
  for (int j = 0; j < 4; ++j) {
    inv4[0][j] = __shfl(i0, fq * 4 + j, 64);
    inv4[1][j] = __shfl(i1, fq * 4 + j, 64);
  }
  __syncthreads();  // all waves done with Ks/Vts/Ps
  __hip_bfloat16* Os = (__hip_bfloat16*)smem;  // [128][136]
#pragma unroll
  for (int r2 = 0; r2 < 2; ++r2)
#pragma unroll
    for (int nd = 0; nd < 8; ++nd)
#pragma unroll
      for (int j = 0; j < 4; ++j)
        Os[(w * 32 + r2 * 16 + fq * 4 + j) * 136 + nd * 16 + fr] =
            __float2bfloat16(oacc[r2][nd][j] * inv4[r2][j]);
  __syncthreads();
#pragma unroll
  for (int it = 0; it < 8; ++it) {
    int i = it * 256 + tid;
    int row = i >> 4, ch = i & 15;
    *(bf16x8*)&O[(size_t)(b * PS + q0 + row) * PE + h * 128 + ch * 8] =
        *(const bf16x8*)&Os[row * 136 + ch * 8];
  }
}

// ---------------------------------------------------------------------------
extern "C" void kernel_launch(void* const* d_in, const int* in_sizes, int n_in,
                              void* d_out, int out_size, void* d_ws, size_t ws_size,
                              hipStream_t stream) {
  const float* x     = (const float*)d_in[0];
  const float* Wqkvh = (const float*)d_in[1];
  const float* Wout  = (const float*)d_in[2];
  float* out = (float*)d_out;

  char* wsb = (char*)d_ws;
  __hip_bfloat16* proj = (__hip_bfloat16*)wsb;          // [4096][6144] bf16
  wsb += (size_t)PM * PQKV * 2;
  __hip_bfloat16* xb = (__hip_bfloat16*)wsb;            // reused as attn out
  wsb += (size_t)PM * PE * 2;
  __hip_bfloat16* Wq_t = (__hip_bfloat16*)wsb;
  wsb += (size_t)PQKV * PE * 2;
  __hip_bfloat16* Wout_t = (__hip_bfloat16*)wsb;
  wsb += (size_t)PE * PE * 2;
  __hip_bfloat16* Vtp = (__hip_bfloat16*)wsb;           // [32][128][2048]
  wsb += (size_t)PB * PH * PD * PS * 2;
  float* hgbuf = (float*)wsb;
  wsb += (size_t)PB * PH * PS * 4;
  float* csum = (float*)wsb;

  // 0) casts / weight transposes
  cast_f32_bf16<<<(PM * PE / 4 + 255) / 256, 256, 0, stream>>>(x, xb, PM * PE / 4);
  transpose_cast<<<dim3(PQKV / 32, PE / 32), 256, 0, stream>>>(Wqkvh, Wq_t, PN_PROJ, PE, 0);
  transpose_cast<<<dim3(PE / 32, PE / 32), 256, 0, stream>>>(Wout, Wout_t, PE, PE, 0);

  // 1) proj = x @ W_qkvh[:, :6144]  (bf16 out)
  gemm_bf16_bt<__hip_bfloat16><<<dim3(PQKV / 128, PM / 128), 256, 0, stream>>>(
      xb, Wq_t, proj, PE, PQKV);

  // 2) gate head + causal weighted cumsum (bf16 in place, pre-scaled)
  hg_from_x<<<PM, 256, 0, stream>>>(x, Wqkvh, hgbuf);
  kc_pass1<<<PB * PH * 16, 128, 0, stream>>>(proj, hgbuf, csum);
  kc_pass2<<<PB * PH * 16, 128, 0, stream>>>(proj, hgbuf, csum);

  // 3) V^T pack + MFMA flash attention -> xb
  vt_pack<<<PB * PH * 32, 256, 0, stream>>>(proj, Vtp);
  __hip_bfloat16* Ob = xb;
  attn_mfma<<<PB * PH * (PS / 128), 256, 0, stream>>>(proj, Vtp, Ob);

  // 4) out = Oattn @ W_out (fp32 out)
  gemm_bf16_bt<float><<<dim3(PE / 128, PM / 128), 256, 0, stream>>>(
      Ob, Wout_t, out, PE, PE);
}

// Round 6
// 368.246 us; speedup vs baseline: 9.0513x; 1.1428x over previous
//
#include <hip/hip_runtime.h>
#include <hip/hip_bf16.h>
#include <math.h>

// Problem constants: B=2, S=2048, E=2048, HEADS=16, d=128
#define PB 2
#define PS 2048
#define PE 2048
#define PH 16
#define PD 128
#define PN_PROJ 6160   // 3*E + HEADS (fp32 weight layout)
#define PM 4096        // B*S
#define PQKV 6144      // 3*E — bf16 proj row length

typedef __attribute__((ext_vector_type(8))) short bf16x8;
typedef __attribute__((ext_vector_type(4))) float f32x4;

__device__ __forceinline__ void gload_lds16(const void* g, void* l) {
  __builtin_amdgcn_global_load_lds((const __attribute__((address_space(1))) void*)g,
                                   (__attribute__((address_space(3))) void*)l, 16, 0, 0);
}

// ---------------------------------------------------------------------------
// bf16 MFMA GEMM (m97 structure): C[M,N] = A[M,K](bf16 rm) @ Bt[N,K](bf16 rm).
// ---------------------------------------------------------------------------
template <typename OutT>
__global__ __launch_bounds__(256) void gemm_bf16_bt(
    const __hip_bfloat16* __restrict__ A, const __hip_bfloat16* __restrict__ Bt,
    OutT* __restrict__ C, int K, int ldc) {
  __shared__ __align__(16) __hip_bfloat16 As[128 * 32];
  __shared__ __align__(16) __hip_bfloat16 Bs[128 * 32];
  const int tid = threadIdx.x;
  const int wave = tid >> 6, lane = tid & 63;
  const int wr = wave >> 1, wc = wave & 1;
  const int fr = lane & 15, fq = lane >> 4;
  const int mBase = blockIdx.y * 128, nBase = blockIdx.x * 128;
  const int rSeg = lane >> 2;
  const int k8 = (lane & 3) * 8;

  f32x4 acc[4][4];
#pragma unroll
  for (int m = 0; m < 4; ++m)
#pragma unroll
    for (int n = 0; n < 4; ++n) acc[m][n] = (f32x4){0.f, 0.f, 0.f, 0.f};

  for (int kt = 0; kt < K; kt += 32) {
    __syncthreads();
#pragma unroll
    for (int i = 0; i < 2; ++i) {
      int seg = i * 4 + wave;
      int row = seg * 16 + rSeg;
      gload_lds16(&A[(size_t)(mBase + row) * K + kt + k8], &As[seg * 512]);
      gload_lds16(&Bt[(size_t)(nBase + row) * K + kt + k8], &Bs[seg * 512]);
    }
    __syncthreads();

    bf16x8 av[4], bv[4];
#pragma unroll
    for (int m = 0; m < 4; ++m)
      av[m] = *(const bf16x8*)&As[(wr * 64 + m * 16 + fr) * 32 + fq * 8];
#pragma unroll
    for (int n = 0; n < 4; ++n)
      bv[n] = *(const bf16x8*)&Bs[(wc * 64 + n * 16 + fr) * 32 + fq * 8];
#pragma unroll
    for (int m = 0; m < 4; ++m)
#pragma unroll
      for (int n = 0; n < 4; ++n)
        acc[m][n] = __builtin_amdgcn_mfma_f32_16x16x32_bf16(av[m], bv[n], acc[m][n], 0, 0, 0);
  }

#pragma unroll
  for (int m = 0; m < 4; ++m) {
#pragma unroll
    for (int n = 0; n < 4; ++n) {
      int row0 = mBase + wr * 64 + m * 16 + fq * 4;
      int col = nBase + wc * 64 + n * 16 + fr;
#pragma unroll
      for (int j = 0; j < 4; ++j) {
        if constexpr (__is_same(OutT, float))
          C[(size_t)(row0 + j) * ldc + col] = acc[m][n][j];
        else
          C[(size_t)(row0 + j) * ldc + col] = __float2bfloat16(acc[m][n][j]);
      }
    }
  }
}

// ---------------------------------------------------------------------------
__global__ __launch_bounds__(256) void cast_f32_bf16(const float* __restrict__ in,
                                                     __hip_bfloat16* __restrict__ out,
                                                     int n4) {
  int i = blockIdx.x * 256 + threadIdx.x;
  if (i >= n4) return;
  float4 v = ((const float4*)in)[i];
  union { __hip_bfloat16 h[4]; uint2 u; } pk;
  pk.h[0] = __float2bfloat16(v.x); pk.h[1] = __float2bfloat16(v.y);
  pk.h[2] = __float2bfloat16(v.z); pk.h[3] = __float2bfloat16(v.w);
  ((uint2*)out)[i] = pk.u;
}

// ---------------------------------------------------------------------------
__global__ __launch_bounds__(256) void transpose_cast(const float* __restrict__ W,
                                                      __hip_bfloat16* __restrict__ Wt,
                                                      int ldw, int ldt, int nOff) {
  __shared__ float t[32][33];
  int nb = blockIdx.x * 32, kb = blockIdx.y * 32;
  int tx = threadIdx.x & 31, ty = threadIdx.x >> 5;
#pragma unroll
  for (int i = 0; i < 4; ++i) {
    int k = ty + i * 8;
    t[k][tx] = W[(size_t)(kb + k) * ldw + nOff + nb + tx];
  }
  __syncthreads();
#pragma unroll
  for (int i = 0; i < 4; ++i) {
    int n = ty + i * 8;
    Wt[(size_t)(nb + n) * ldt + kb + tx] = __float2bfloat16(t[tx][n]);
  }
}

// ---------------------------------------------------------------------------
// Gate head from x (fp32): hgbuf[(b*H+h)*S+s] = tanh(x[bs,:] . W[:,3E+h])
// ---------------------------------------------------------------------------
__global__ __launch_bounds__(256) void hg_from_x(const float* __restrict__ x,
                                                 const float* __restrict__ W,
                                                 float* __restrict__ hgbuf) {
  int bs = blockIdx.x;
  int b = bs >> 11, s = bs & (PS - 1);
  __shared__ float xs[PE];
  __shared__ float red[16][17];
  const float* xr = x + (size_t)bs * PE;
  for (int i = threadIdx.x; i < PE / 4; i += 256)
    *(float4*)&xs[i * 4] = ((const float4*)xr)[i];
  __syncthreads();
  int h = threadIdx.x & 15, part = threadIdx.x >> 4;
  float acc = 0.f;
  for (int k = part * 128; k < part * 128 + 128; ++k)
    acc += xs[k] * W[(size_t)k * PN_PROJ + 3 * PE + h];
  red[part][h] = acc;
  __syncthreads();
  if (threadIdx.x < 16) {
    float sm = 0.f;
#pragma unroll
    for (int p = 0; p < 16; ++p) sm += red[p][threadIdx.x];
    hgbuf[(size_t)(b * PH + threadIdx.x) * PS + s] = tanhf(sm);
  }
}

// ---------------------------------------------------------------------------
// Kc scan on bf16 proj (fp32 accumulation). Kc written back as bf16,
// PRE-SCALED by 1/sqrt(E).
// ---------------------------------------------------------------------------
#define KC_SCALE 0.022097086912079608f  // 1/sqrt(2048)

__global__ __launch_bounds__(128) void kc_pass1(const __hip_bfloat16* __restrict__ proj,
                                                const float* __restrict__ hgbuf,
                                                float* __restrict__ csum) {
  int c = blockIdx.x & 15, bh = blockIdx.x >> 4;
  int h = bh & (PH - 1), b = bh >> 4;
  int d = threadIdx.x;
  __shared__ float hgs[128];
  hgs[d] = hgbuf[bh * PS + c * 128 + d];
  __syncthreads();
  const __hip_bfloat16* kbase = proj + (size_t)(b * PS) * PQKV + h * 384 + 128 + d;
  float acc = 0.f;
  int j0 = c * 128;
  for (int i = 0; i < 128; ++i) {
    int j = j0 + i;
    acc += (float)(j + 1) * hgs[i] * __bfloat162float(kbase[(size_t)j * PQKV]);
  }
  csum[blockIdx.x * 128 + d] = acc;
}

__global__ __launch_bounds__(128) void kc_pass2(__hip_bfloat16* __restrict__ proj,
                                                const float* __restrict__ hgbuf,
                                                const float* __restrict__ csum) {
  int c = blockIdx.x & 15, bh = blockIdx.x >> 4;
  int h = bh & (PH - 1), b = bh >> 4;
  int d = threadIdx.x;
  __shared__ float hgs[128];
  hgs[d] = hgbuf[bh * PS + c * 128 + d];
  __syncthreads();
  float acc = 0.f;
  for (int cc = 0; cc < c; ++cc) acc += csum[(bh * 16 + cc) * 128 + d];
  __hip_bfloat16* kbase = proj + (size_t)(b * PS) * PQKV + h * 384 + 128 + d;
  int j0 = c * 128;
  for (int i = 0; i < 128; ++i) {
    int j = j0 + i;
    acc += (float)(j + 1) * hgs[i] * __bfloat162float(kbase[(size_t)j * PQKV]);
    float t = (float)(j + 1);
    kbase[(size_t)j * PQKV] = __float2bfloat16(acc / (t * t) * KC_SCALE);
  }
}

// ---------------------------------------------------------------------------
// V^T pack: Vtp[bh][d][s]
// ---------------------------------------------------------------------------
__global__ __launch_bounds__(256) void vt_pack(const __hip_bfloat16* __restrict__ proj,
                                               __hip_bfloat16* __restrict__ Vtp) {
  int sc = blockIdx.x & 31, bh = blockIdx.x >> 5;
  int b = bh >> 4, h = bh & 15;
  int s0 = sc * 64;
  int tid = threadIdx.x;
  __shared__ __align__(16) __hip_bfloat16 Vlds[64][136];
  const __hip_bfloat16* src = proj + (size_t)(b * PS + s0) * PQKV + h * 384 + 256;
#pragma unroll
  for (int it = 0; it < 4; ++it) {
    int i = it * 256 + tid;
    int row = i >> 4, ch = i & 15;
    *(bf16x8*)&Vlds[row][ch * 8] = *(const bf16x8*)&src[(size_t)row * PQKV + ch * 8];
  }
  __syncthreads();
  int d = tid >> 1, half = tid & 1;
  __hip_bfloat16* dst = Vtp + ((size_t)bh * 128 + d) * PS + s0 + half * 32;
#pragma unroll
  for (int c8 = 0; c8 < 8; ++c8) {
    union { __hip_bfloat16 h4[4]; uint2 u; } pk;
#pragma unroll
    for (int k = 0; k < 4; ++k) pk.h4[k] = Vlds[half * 32 + c8 * 4 + k][d];
    *(uint2*)&dst[c8 * 4] = pk.u;
  }
}

// ---------------------------------------------------------------------------
// MFMA flash attention v3.
// Grid = 256 blocks: (bh, pk in 0..7). Each block processes q-tile pk THEN
// q-tile 15-pk -> uniform 34 KV-iters/block (causal load balance).
// 4 waves, QBLK=128 (32 q-rows/wave, 2 rowgroups), KVBLK=64.
// Double-buffered KV staging via global_load_lds (issue next tile before
// computing current; single __syncthreads per iter drains vmcnt after the
// compute has covered the latency). Swapped QK^T, defer-max, XOR-swizzled
// K/V LDS (pre-swizzled global source, linear LDS dest).
// ---------------------------------------------------------------------------
__global__ __launch_bounds__(256) void attn_mfma(const __hip_bfloat16* __restrict__ proj,
                                                 const __hip_bfloat16* __restrict__ Vtp,
                                                 __hip_bfloat16* __restrict__ O) {
  // XCD chunking: 32 consecutive logical blocks (4 bh) per XCD
  const int bid = (blockIdx.x & 7) * 32 + (blockIdx.x >> 3);
  const int bh = bid >> 3, pk = bid & 7;
  const int b = bh >> 4, h = bh & 15;
  const int tid = threadIdx.x;
  const int w = tid >> 6, lane = tid & 63;
  const int fq = lane >> 4, fr = lane & 15;

  // LDS: Ks dbuf @0 (2x16K) | Vts dbuf @32K (2x16K) | Ps @64K (18K) | Os @84K (35K)
  __shared__ __align__(16) char smem[120832];
  __hip_bfloat16* Psw = (__hip_bfloat16*)(smem + 65536) + w * 32 * 72;
  __hip_bfloat16* Os = (__hip_bfloat16*)(smem + 84480);

  const __hip_bfloat16* kb0 = proj + (size_t)(b * PS) * PQKV + h * 384 + 128;
  const __hip_bfloat16* vb0 = Vtp + (size_t)bh * 128 * PS;

  const int klr = lane >> 4, kc = lane & 15;  // K staging: 4 rows x 16 chunks
  const int vlr = lane >> 3, vc = lane & 7;   // V staging: 8 rows x 8 chunks

  auto stageKV = [&](int t, int bufi) {
    char* ksb = smem + bufi * 16384;
    char* vsb = smem + 32768 + bufi * 16384;
    const __hip_bfloat16* kb = kb0 + (size_t)(t * 64) * PQKV;
    const __hip_bfloat16* vb = vb0 + t * 64;
#pragma unroll
    for (int p = 0; p < 4; ++p) {
      int row = w * 16 + p * 4 + klr;
      int cs = kc ^ (row & 7);
      gload_lds16(kb + (size_t)row * PQKV + cs * 8, ksb + (w * 16 + p * 4) * 256);
    }
#pragma unroll
    for (int p = 0; p < 4; ++p) {
      int row = w * 32 + p * 8 + vlr;
      int cs = vc ^ (row & 7);
      gload_lds16(vb + (size_t)row * PS + cs * 8, vsb + (w * 32 + p * 8) * 128);
    }
  };

  stageKV(0, 0);
  int cur = 0;

#pragma unroll 1
  for (int phase = 0; phase < 2; ++phase) {
    const int qt = (phase == 0) ? pk : 15 - pk;
    const int nt = (qt + 1) * 2;
    const int q0 = qt * 128;
    const int qw = q0 + w * 32;

    // Q fragments for this phase
    const __hip_bfloat16* qbase = proj + (size_t)(b * PS + qw) * PQKV + h * 384;
    bf16x8 qf[2][4];
#pragma unroll
    for (int r2 = 0; r2 < 2; ++r2)
#pragma unroll
      for (int kk = 0; kk < 4; ++kk)
        qf[r2][kk] = *(const bf16x8*)&qbase[(size_t)(r2 * 16 + fr) * PQKV + kk * 32 + fq * 8];

    f32x4 oacc[2][8];
#pragma unroll
    for (int r2 = 0; r2 < 2; ++r2)
#pragma unroll
      for (int nd = 0; nd < 8; ++nd) oacc[r2][nd] = (f32x4){0.f, 0.f, 0.f, 0.f};
    float m_[2] = {-__builtin_inff(), -__builtin_inff()};
    float l_[2] = {0.f, 0.f};

#pragma unroll 1
    for (int kt = 0; kt < nt; ++kt) {
      // prefetch next tile (next kt, or tile 0 of phase B) into the other buf
      const bool hasNext = (kt + 1 < nt) || (phase == 0);
      if (hasNext) stageKV((kt + 1 < nt) ? kt + 1 : 0, cur ^ 1);

      if (kt * 64 <= qw + 31) {  // tile intersects this wave's causal band
        const __hip_bfloat16* Ks = (const __hip_bfloat16*)(smem + cur * 16384);
        const __hip_bfloat16* Vts = (const __hip_bfloat16*)(smem + 32768 + cur * 16384);
        const bool diag = (kt * 64 + 63) > qw;

        // QK^T swapped: sacc[r2][n][j] = S[k=kt*64+n*16+fq*4+j][q=qw+r2*16+fr]
        f32x4 sacc[2][4];
#pragma unroll
        for (int r2 = 0; r2 < 2; ++r2)
#pragma unroll
          for (int n = 0; n < 4; ++n) sacc[r2][n] = (f32x4){0.f, 0.f, 0.f, 0.f};
#pragma unroll
        for (int kk = 0; kk < 4; ++kk) {
#pragma unroll
          for (int n = 0; n < 4; ++n) {
            bf16x8 kf = *(const bf16x8*)&Ks[(n * 16 + fr) * 128 + (((kk * 4 + fq) ^ (fr & 7)) * 8)];
            sacc[0][n] = __builtin_amdgcn_mfma_f32_16x16x32_bf16(kf, qf[0][kk], sacc[0][n], 0, 0, 0);
            sacc[1][n] = __builtin_amdgcn_mfma_f32_16x16x32_bf16(kf, qf[1][kk], sacc[1][n], 0, 0, 0);
          }
        }

        // softmax + P write per rowgroup
#pragma unroll
        for (int r2 = 0; r2 < 2; ++r2) {
          const int qg = qw + r2 * 16 + fr;
          float sv[4][4];
#pragma unroll
          for (int n = 0; n < 4; ++n)
#pragma unroll
            for (int j = 0; j < 4; ++j) {
              float s = sacc[r2][n][j];
              if (diag && (kt * 64 + n * 16 + fq * 4 + j) > qg) s = -__builtin_inff();
              sv[n][j] = s;
            }
          float pmax = sv[0][0];
#pragma unroll
          for (int n = 0; n < 4; ++n)
#pragma unroll
            for (int j = 0; j < 4; ++j) pmax = fmaxf(pmax, sv[n][j]);
          pmax = fmaxf(pmax, __shfl_xor(pmax, 16, 64));
          pmax = fmaxf(pmax, __shfl_xor(pmax, 32, 64));

          const bool nof = __all(pmax <= m_[r2] + 8.f);  // defer-max (T13)
          const float mn = nof ? m_[r2] : fmaxf(m_[r2], pmax);
          float ps = 0.f;
#pragma unroll
          for (int n = 0; n < 4; ++n) {
            union { __hip_bfloat16 hh[4]; uint2 u; } pkk;
#pragma unroll
            for (int j = 0; j < 4; ++j) {
              float p = __expf(sv[n][j] - mn);
              ps += p;
              pkk.hh[j] = __float2bfloat16(p);
            }
            *(uint2*)&Psw[(r2 * 16 + fr) * 72 + n * 16 + fq * 4] = pkk.u;
          }
          ps += __shfl_xor(ps, 16, 64);
          ps += __shfl_xor(ps, 32, 64);

          if (!nof) {
            const float alpha = __expf(m_[r2] - mn);
            l_[r2] = l_[r2] * alpha + ps;
            m_[r2] = mn;
            float a0 = __shfl(alpha, fq * 4 + 0, 64);
            float a1 = __shfl(alpha, fq * 4 + 1, 64);
            float a2 = __shfl(alpha, fq * 4 + 2, 64);
            float a3 = __shfl(alpha, fq * 4 + 3, 64);
#pragma unroll
            for (int nd = 0; nd < 8; ++nd) {
              oacc[r2][nd][0] *= a0; oacc[r2][nd][1] *= a1;
              oacc[r2][nd][2] *= a2; oacc[r2][nd][3] *= a3;
            }
          } else {
            l_[r2] += ps;
          }
        }

        // PV: oacc[r2][nd] += P(16x64) . V(64x128)
#pragma unroll
        for (int kk2 = 0; kk2 < 2; ++kk2) {
          bf16x8 pa0 = *(const bf16x8*)&Psw[(0 * 16 + fr) * 72 + kk2 * 32 + fq * 8];
          bf16x8 pa1 = *(const bf16x8*)&Psw[(1 * 16 + fr) * 72 + kk2 * 32 + fq * 8];
#pragma unroll
          for (int nd = 0; nd < 8; ++nd) {
            bf16x8 vf = *(const bf16x8*)&Vts[(nd * 16 + fr) * 64 + (((kk2 * 4 + fq) ^ (fr & 7)) * 8)];
            oacc[0][nd] = __builtin_amdgcn_mfma_f32_16x16x32_bf16(pa0, vf, oacc[0][nd], 0, 0, 0);
            oacc[1][nd] = __builtin_amdgcn_mfma_f32_16x16x32_bf16(pa1, vf, oacc[1][nd], 0, 0, 0);
          }
        }
      }

      __syncthreads();  // drains vmcnt (prefetch landed) + all waves done with buf[cur]
      cur ^= 1;
    }

    // phase epilogue: normalize, stage O (bf16) in dedicated Os, coalesced store
    float i0 = 1.0f / l_[0], i1 = 1.0f / l_[1];
    float inv4[2][4];
#pragma unroll
    for (int j = 0; j < 4; ++j) {
      inv4[0][j] = __shfl(i0, fq * 4 + j, 64);
      inv4[1][j] = __shfl(i1, fq * 4 + j, 64);
    }
#pragma unroll
    for (int r2 = 0; r2 < 2; ++r2)
#pragma unroll
      for (int nd = 0; nd < 8; ++nd)
#pragma unroll
        for (int j = 0; j < 4; ++j)
          Os[(w * 32 + r2 * 16 + fq * 4 + j) * 136 + nd * 16 + fr] =
              __float2bfloat16(oacc[r2][nd][j] * inv4[r2][j]);
    __syncthreads();
#pragma unroll
    for (int it = 0; it < 8; ++it) {
      int i = it * 256 + tid;
      int row = i >> 4, ch = i & 15;
      *(bf16x8*)&O[(size_t)(b * PS + q0 + row) * PE + h * 128 + ch * 8] =
          *(const bf16x8*)&Os[row * 136 + ch * 8];
    }
  }
}

// ---------------------------------------------------------------------------
extern "C" void kernel_launch(void* const* d_in, const int* in_sizes, int n_in,
                              void* d_out, int out_size, void* d_ws, size_t ws_size,
                              hipStream_t stream) {
  const float* x     = (const float*)d_in[0];
  const float* Wqkvh = (const float*)d_in[1];
  const float* Wout  = (const float*)d_in[2];
  float* out = (float*)d_out;

  char* wsb = (char*)d_ws;
  __hip_bfloat16* proj = (__hip_bfloat16*)wsb;          // [4096][6144] bf16
  wsb += (size_t)PM * PQKV * 2;
  __hip_bfloat16* xb = (__hip_bfloat16*)wsb;            // reused as attn out
  wsb += (size_t)PM * PE * 2;
  __hip_bfloat16* Wq_t = (__hip_bfloat16*)wsb;
  wsb += (size_t)PQKV * PE * 2;
  __hip_bfloat16* Wout_t = (__hip_bfloat16*)wsb;
  wsb += (size_t)PE * PE * 2;
  __hip_bfloat16* Vtp = (__hip_bfloat16*)wsb;           // [32][128][2048]
  wsb += (size_t)PB * PH * PD * PS * 2;
  float* hgbuf = (float*)wsb;
  wsb += (size_t)PB * PH * PS * 4;
  float* csum = (float*)wsb;

  // 0) casts / weight transposes
  cast_f32_bf16<<<(PM * PE / 4 + 255) / 256, 256, 0, stream>>>(x, xb, PM * PE / 4);
  transpose_cast<<<dim3(PQKV / 32, PE / 32), 256, 0, stream>>>(Wqkvh, Wq_t, PN_PROJ, PE, 0);
  transpose_cast<<<dim3(PE / 32, PE / 32), 256, 0, stream>>>(Wout, Wout_t, PE, PE, 0);

  // 1) proj = x @ W_qkvh[:, :6144]  (bf16 out)
  gemm_bf16_bt<__hip_bfloat16><<<dim3(PQKV / 128, PM / 128), 256, 0, stream>>>(
      xb, Wq_t, proj, PE, PQKV);

  // 2) gate head + causal weighted cumsum (bf16 in place, pre-scaled)
  hg_from_x<<<PM, 256, 0, stream>>>(x, Wqkvh, hgbuf);
  kc_pass1<<<PB * PH * 16, 128, 0, stream>>>(proj, hgbuf, csum);
  kc_pass2<<<PB * PH * 16, 128, 0, stream>>>(proj, hgbuf, csum);

  // 3) V^T pack + MFMA flash attention -> xb
  vt_pack<<<PB * PH * 32, 256, 0, stream>>>(proj, Vtp);
  __hip_bfloat16* Ob = xb;
  attn_mfma<<<PB * PH * 8, 256, 0, stream>>>(proj, Vtp, Ob);

  // 4) out = Oattn @ W_out (fp32 out)
  gemm_bf16_bt<float><<<dim3(PE / 128, PM / 128), 256, 0, stream>>>(
      Ob, Wout_t, out, PE, PE);
}

// Round 7
// 348.342 us; speedup vs baseline: 9.5685x; 1.0571x over previous
//
#include <hip/hip_runtime.h>
#include <hip/hip_bf16.h>
#include <math.h>

// Problem constants: B=2, S=2048, E=2048, HEADS=16, d=128
#define PB 2
#define PS 2048
#define PE 2048
#define PH 16
#define PD 128
#define PN_PROJ 6160   // 3*E + HEADS (fp32 weight layout)
#define PM 4096        // B*S
#define PQKV 6144      // 3*E — bf16 proj row length

typedef __attribute__((ext_vector_type(8))) short bf16x8;
typedef __attribute__((ext_vector_type(4))) float f32x4;

__device__ __forceinline__ void gload_lds16(const void* g, void* l) {
  __builtin_amdgcn_global_load_lds((const __attribute__((address_space(1))) void*)g,
                                   (__attribute__((address_space(3))) void*)l, 16, 0, 0);
}

// ---------------------------------------------------------------------------
// Counted-vmcnt double-buffered bf16 MFMA GEMM.
// C[M,N] = A[M,K](bf16 rm) @ Bt[N,K](bf16 rm). BK=64.
// Waves: WM x WN (per-wave tile (BM/WM) x (BN/WN)); T = WM*WN*64 threads.
// LDS: 2 buffers x (A[BM][64] + B[BN][64]), XOR-swizzled chunks (c ^= row&7)
// staged via global_load_lds with pre-swizzled GLOBAL source (linear LDS dest).
// Schedule: stage t0,t1; loop { vmcnt(NLD) ; barrier ; phases(MFMA) ;
// lgkmcnt(0) ; barrier ; stage(t+2) }  — vmcnt never drains to 0 mid-loop.
// ---------------------------------------------------------------------------
template <int BM, int BN, int WM, int WN, typename OutT>
__global__ __launch_bounds__(WM * WN * 64, 2) void gemm_8p(
    const __hip_bfloat16* __restrict__ A, const __hip_bfloat16* __restrict__ Bt,
    OutT* __restrict__ C, int K, int lda, int ldb, int ldc, int nTilesX) {
  constexpr int BK = 64;
  constexpr int T = WM * WN * 64;
  constexpr int AR = BM * BK * 2 / (T * 16);   // A stage rounds (16B/thread each)
  constexpr int BR = BN * BK * 2 / (T * 16);
  constexpr int NLD = AR + BR;                 // gload_lds per thread per K-tile
  constexpr int MF = BM / WM / 16;             // m-frags per wave
  constexpr int NF = BN / WN / 16;             // n-frags per wave
  constexpr int BUFE = (BM + BN) * BK;         // elements per buffer

  __shared__ __align__(16) __hip_bfloat16 smem[2 * BUFE];

  const int tid = threadIdx.x;
  const int w = tid >> 6, lane = tid & 63;
  const int fq = lane >> 4, fr = lane & 15;
  const int wm = w / WN, wn = w % WN;

  // bijective XCD swizzle (gridDim.x % 8 == 0)
  const int total = gridDim.x;
  const int swz = (blockIdx.x & 7) * (total >> 3) + (blockIdx.x >> 3);
  const int mBase = (swz / nTilesX) * BM;
  const int nBase = (swz % nTilesX) * BN;

  auto stage = [&](int t, int buf) {
    char* ab = (char*)smem + (size_t)buf * BUFE * 2;
    char* bb = ab + BM * BK * 2;
    const int wub = tid & ~63;  // wave-uniform thread base
#pragma unroll
    for (int p = 0; p < AR; ++p) {
      int g = p * T + tid;
      int row = g >> 3, c = g & 7;
      int cs = c ^ (row & 7);
      gload_lds16(A + (size_t)(mBase + row) * lda + t * BK + cs * 8,
                  ab + (size_t)(p * T + wub) * 16);
    }
#pragma unroll
    for (int p = 0; p < BR; ++p) {
      int g = p * T + tid;
      int row = g >> 3, c = g & 7;
      int cs = c ^ (row & 7);
      gload_lds16(Bt + (size_t)(nBase + row) * ldb + t * BK + cs * 8,
                  bb + (size_t)(p * T + wub) * 16);
    }
  };

  f32x4 acc[MF][NF];
#pragma unroll
  for (int m = 0; m < MF; ++m)
#pragma unroll
    for (int n = 0; n < NF; ++n) acc[m][n] = (f32x4){0.f, 0.f, 0.f, 0.f};

  const int NT = K / BK;
  stage(0, 0);
  stage(1, 1);

#pragma unroll 1
  for (int t = 0; t < NT; ++t) {
    if (t + 1 < NT) asm volatile("s_waitcnt vmcnt(%0)" ::"i"(NLD) : "memory");
    else            asm volatile("s_waitcnt vmcnt(0)" ::: "memory");
    __builtin_amdgcn_s_barrier();
    __builtin_amdgcn_sched_barrier(0);

    const __hip_bfloat16* As = smem + (size_t)(t & 1) * BUFE;
    const __hip_bfloat16* Bs = As + BM * BK;

#pragma unroll
    for (int mh = 0; mh < MF / 4; ++mh) {
      bf16x8 av[4][2];
#pragma unroll
      for (int m = 0; m < 4; ++m)
#pragma unroll
        for (int kk = 0; kk < 2; ++kk) {
          int row = wm * (BM / WM) + (mh * 4 + m) * 16 + fr;
          av[m][kk] = *(const bf16x8*)&As[row * BK + (((kk * 4 + fq) ^ (row & 7)) * 8)];
        }
#pragma unroll
      for (int nh = 0; nh < NF / 2; ++nh) {
        bf16x8 bv[2][2];
#pragma unroll
        for (int n = 0; n < 2; ++n)
#pragma unroll
          for (int kk = 0; kk < 2; ++kk) {
            int row = wn * (BN / WN) + (nh * 2 + n) * 16 + fr;
            bv[n][kk] = *(const bf16x8*)&Bs[row * BK + (((kk * 4 + fq) ^ (row & 7)) * 8)];
          }
        __builtin_amdgcn_s_setprio(1);
#pragma unroll
        for (int m = 0; m < 4; ++m)
#pragma unroll
          for (int n = 0; n < 2; ++n)
#pragma unroll
            for (int kk = 0; kk < 2; ++kk)
              acc[mh * 4 + m][nh * 2 + n] = __builtin_amdgcn_mfma_f32_16x16x32_bf16(
                  av[m][kk], bv[n][kk], acc[mh * 4 + m][nh * 2 + n], 0, 0, 0);
        __builtin_amdgcn_s_setprio(0);
      }
    }

    __builtin_amdgcn_sched_barrier(0);
    asm volatile("s_waitcnt lgkmcnt(0)" ::: "memory");
    __builtin_amdgcn_s_barrier();
    if (t + 2 < NT) stage(t + 2, t & 1);
  }

  // epilogue: C/D layout col=lane&15, row=(lane>>4)*4+reg (m89-verified)
#pragma unroll
  for (int m = 0; m < MF; ++m) {
#pragma unroll
    for (int n = 0; n < NF; ++n) {
      int row0 = mBase + wm * (BM / WM) + m * 16 + fq * 4;
      int col = nBase + wn * (BN / WN) + n * 16 + fr;
#pragma unroll
      for (int j = 0; j < 4; ++j) {
        if constexpr (__is_same(OutT, float))
          C[(size_t)(row0 + j) * ldc + col] = acc[m][n][j];
        else
          C[(size_t)(row0 + j) * ldc + col] = __float2bfloat16(acc[m][n][j]);
      }
    }
  }
}

// ---------------------------------------------------------------------------
__global__ __launch_bounds__(256) void cast_f32_bf16(const float* __restrict__ in,
                                                     __hip_bfloat16* __restrict__ out,
                                                     int n4) {
  int i = blockIdx.x * 256 + threadIdx.x;
  if (i >= n4) return;
  float4 v = ((const float4*)in)[i];
  union { __hip_bfloat16 h[4]; uint2 u; } pk;
  pk.h[0] = __float2bfloat16(v.x); pk.h[1] = __float2bfloat16(v.y);
  pk.h[2] = __float2bfloat16(v.z); pk.h[3] = __float2bfloat16(v.w);
  ((uint2*)out)[i] = pk.u;
}

// ---------------------------------------------------------------------------
__global__ __launch_bounds__(256) void transpose_cast(const float* __restrict__ W,
                                                      __hip_bfloat16* __restrict__ Wt,
                                                      int ldw, int ldt, int nOff) {
  __shared__ float t[32][33];
  int nb = blockIdx.x * 32, kb = blockIdx.y * 32;
  int tx = threadIdx.x & 31, ty = threadIdx.x >> 5;
#pragma unroll
  for (int i = 0; i < 4; ++i) {
    int k = ty + i * 8;
    t[k][tx] = W[(size_t)(kb + k) * ldw + nOff + nb + tx];
  }
  __syncthreads();
#pragma unroll
  for (int i = 0; i < 4; ++i) {
    int n = ty + i * 8;
    Wt[(size_t)(nb + n) * ldt + kb + tx] = __float2bfloat16(t[tx][n]);
  }
}

// ---------------------------------------------------------------------------
// Gate head from x (fp32): hgbuf[(b*H+h)*S+s] = tanh(x[bs,:] . W[:,3E+h])
// ---------------------------------------------------------------------------
__global__ __launch_bounds__(256) void hg_from_x(const float* __restrict__ x,
                                                 const float* __restrict__ W,
                                                 float* __restrict__ hgbuf) {
  int bs = blockIdx.x;
  int b = bs >> 11, s = bs & (PS - 1);
  __shared__ float xs[PE];
  __shared__ float red[16][17];
  const float* xr = x + (size_t)bs * PE;
  for (int i = threadIdx.x; i < PE / 4; i += 256)
    *(float4*)&xs[i * 4] = ((const float4*)xr)[i];
  __syncthreads();
  int h = threadIdx.x & 15, part = threadIdx.x >> 4;
  float acc = 0.f;
  for (int k = part * 128; k < part * 128 + 128; ++k)
    acc += xs[k] * W[(size_t)k * PN_PROJ + 3 * PE + h];
  red[part][h] = acc;
  __syncthreads();
  if (threadIdx.x < 16) {
    float sm = 0.f;
#pragma unroll
    for (int p = 0; p < 16; ++p) sm += red[p][threadIdx.x];
    hgbuf[(size_t)(b * PH + threadIdx.x) * PS + s] = tanhf(sm);
  }
}

// ---------------------------------------------------------------------------
// Kc scan on bf16 proj (fp32 accumulation), pre-scaled by 1/sqrt(E).
// ---------------------------------------------------------------------------
#define KC_SCALE 0.022097086912079608f  // 1/sqrt(2048)

__global__ __launch_bounds__(128) void kc_pass1(const __hip_bfloat16* __restrict__ proj,
                                                const float* __restrict__ hgbuf,
                                                float* __restrict__ csum) {
  int c = blockIdx.x & 15, bh = blockIdx.x >> 4;
  int h = bh & (PH - 1), b = bh >> 4;
  int d = threadIdx.x;
  __shared__ float hgs[128];
  hgs[d] = hgbuf[bh * PS + c * 128 + d];
  __syncthreads();
  const __hip_bfloat16* kbase = proj + (size_t)(b * PS) * PQKV + h * 384 + 128 + d;
  float acc = 0.f;
  int j0 = c * 128;
  for (int i = 0; i < 128; ++i) {
    int j = j0 + i;
    acc += (float)(j + 1) * hgs[i] * __bfloat162float(kbase[(size_t)j * PQKV]);
  }
  csum[blockIdx.x * 128 + d] = acc;
}

__global__ __launch_bounds__(128) void kc_pass2(__hip_bfloat16* __restrict__ proj,
                                                const float* __restrict__ hgbuf,
                                                const float* __restrict__ csum) {
  int c = blockIdx.x & 15, bh = blockIdx.x >> 4;
  int h = bh & (PH - 1), b = bh >> 4;
  int d = threadIdx.x;
  __shared__ float hgs[128];
  hgs[d] = hgbuf[bh * PS + c * 128 + d];
  __syncthreads();
  float acc = 0.f;
  for (int cc = 0; cc < c; ++cc) acc += csum[(bh * 16 + cc) * 128 + d];
  __hip_bfloat16* kbase = proj + (size_t)(b * PS) * PQKV + h * 384 + 128 + d;
  int j0 = c * 128;
  for (int i = 0; i < 128; ++i) {
    int j = j0 + i;
    acc += (float)(j + 1) * hgs[i] * __bfloat162float(kbase[(size_t)j * PQKV]);
    float t = (float)(j + 1);
    kbase[(size_t)j * PQKV] = __float2bfloat16(acc / (t * t) * KC_SCALE);
  }
}

// ---------------------------------------------------------------------------
// V^T pack: Vtp[bh][d][s]
// ---------------------------------------------------------------------------
__global__ __launch_bounds__(256) void vt_pack(const __hip_bfloat16* __restrict__ proj,
                                               __hip_bfloat16* __restrict__ Vtp) {
  int sc = blockIdx.x & 31, bh = blockIdx.x >> 5;
  int b = bh >> 4, h = bh & 15;
  int s0 = sc * 64;
  int tid = threadIdx.x;
  __shared__ __align__(16) __hip_bfloat16 Vlds[64][136];
  const __hip_bfloat16* src = proj + (size_t)(b * PS + s0) * PQKV + h * 384 + 256;
#pragma unroll
  for (int it = 0; it < 4; ++it) {
    int i = it * 256 + tid;
    int row = i >> 4, ch = i & 15;
    *(bf16x8*)&Vlds[row][ch * 8] = *(const bf16x8*)&src[(size_t)row * PQKV + ch * 8];
  }
  __syncthreads();
  int d = tid >> 1, half = tid & 1;
  __hip_bfloat16* dst = Vtp + ((size_t)bh * 128 + d) * PS + s0 + half * 32;
#pragma unroll
  for (int c8 = 0; c8 < 8; ++c8) {
    union { __hip_bfloat16 h4[4]; uint2 u; } pk;
#pragma unroll
    for (int k = 0; k < 4; ++k) pk.h4[k] = Vlds[half * 32 + c8 * 4 + k][d];
    *(uint2*)&dst[c8 * 4] = pk.u;
  }
}

// ---------------------------------------------------------------------------
// MFMA flash attention v3 (unchanged from round 6; causal-balanced pairing,
// dbuf KV staging, swapped QK^T, defer-max, XOR-swizzled LDS).
// ---------------------------------------------------------------------------
__global__ __launch_bounds__(256) void attn_mfma(const __hip_bfloat16* __restrict__ proj,
                                                 const __hip_bfloat16* __restrict__ Vtp,
                                                 __hip_bfloat16* __restrict__ O) {
  const int bid = (blockIdx.x & 7) * 32 + (blockIdx.x >> 3);
  const int bh = bid >> 3, pk = bid & 7;
  const int b = bh >> 4, h = bh & 15;
  const int tid = threadIdx.x;
  const int w = tid >> 6, lane = tid & 63;
  const int fq = lane >> 4, fr = lane & 15;

  __shared__ __align__(16) char smem[120832];
  __hip_bfloat16* Psw = (__hip_bfloat16*)(smem + 65536) + w * 32 * 72;
  __hip_bfloat16* Os = (__hip_bfloat16*)(smem + 84480);

  const __hip_bfloat16* kb0 = proj + (size_t)(b * PS) * PQKV + h * 384 + 128;
  const __hip_bfloat16* vb0 = Vtp + (size_t)bh * 128 * PS;

  const int klr = lane >> 4, kc = lane & 15;
  const int vlr = lane >> 3, vc = lane & 7;

  auto stageKV = [&](int t, int bufi) {
    char* ksb = smem + bufi * 16384;
    char* vsb = smem + 32768 + bufi * 16384;
    const __hip_bfloat16* kb = kb0 + (size_t)(t * 64) * PQKV;
    const __hip_bfloat16* vb = vb0 + t * 64;
#pragma unroll
    for (int p = 0; p < 4; ++p) {
      int row = w * 16 + p * 4 + klr;
      int cs = kc ^ (row & 7);
      gload_lds16(kb + (size_t)row * PQKV + cs * 8, ksb + (w * 16 + p * 4) * 256);
    }
#pragma unroll
    for (int p = 0; p < 4; ++p) {
      int row = w * 32 + p * 8 + vlr;
      int cs = vc ^ (row & 7);
      gload_lds16(vb + (size_t)row * PS + cs * 8, vsb + (w * 32 + p * 8) * 128);
    }
  };

  stageKV(0, 0);
  int cur = 0;

#pragma unroll 1
  for (int phase = 0; phase < 2; ++phase) {
    const int qt = (phase == 0) ? pk : 15 - pk;
    const int nt = (qt + 1) * 2;
    const int q0 = qt * 128;
    const int qw = q0 + w * 32;

    const __hip_bfloat16* qbase = proj + (size_t)(b * PS + qw) * PQKV + h * 384;
    bf16x8 qf[2][4];
#pragma unroll
    for (int r2 = 0; r2 < 2; ++r2)
#pragma unroll
      for (int kk = 0; kk < 4; ++kk)
        qf[r2][kk] = *(const bf16x8*)&qbase[(size_t)(r2 * 16 + fr) * PQKV + kk * 32 + fq * 8];

    f32x4 oacc[2][8];
#pragma unroll
    for (int r2 = 0; r2 < 2; ++r2)
#pragma unroll
      for (int nd = 0; nd < 8; ++nd) oacc[r2][nd] = (f32x4){0.f, 0.f, 0.f, 0.f};
    float m_[2] = {-__builtin_inff(), -__builtin_inff()};
    float l_[2] = {0.f, 0.f};

#pragma unroll 1
    for (int kt = 0; kt < nt; ++kt) {
      const bool hasNext = (kt + 1 < nt) || (phase == 0);
      if (hasNext) stageKV((kt + 1 < nt) ? kt + 1 : 0, cur ^ 1);

      if (kt * 64 <= qw + 31) {
        const __hip_bfloat16* Ks = (const __hip_bfloat16*)(smem + cur * 16384);
        const __hip_bfloat16* Vts = (const __hip_bfloat16*)(smem + 32768 + cur * 16384);
        const bool diag = (kt * 64 + 63) > qw;

        f32x4 sacc[2][4];
#pragma unroll
        for (int r2 = 0; r2 < 2; ++r2)
#pragma unroll
          for (int n = 0; n < 4; ++n) sacc[r2][n] = (f32x4){0.f, 0.f, 0.f, 0.f};
#pragma unroll
        for (int kk = 0; kk < 4; ++kk) {
#pragma unroll
          for (int n = 0; n < 4; ++n) {
            bf16x8 kf = *(const bf16x8*)&Ks[(n * 16 + fr) * 128 + (((kk * 4 + fq) ^ (fr & 7)) * 8)];
            sacc[0][n] = __builtin_amdgcn_mfma_f32_16x16x32_bf16(kf, qf[0][kk], sacc[0][n], 0, 0, 0);
            sacc[1][n] = __builtin_amdgcn_mfma_f32_16x16x32_bf16(kf, qf[1][kk], sacc[1][n], 0, 0, 0);
          }
        }

#pragma unroll
        for (int r2 = 0; r2 < 2; ++r2) {
          const int qg = qw + r2 * 16 + fr;
          float sv[4][4];
#pragma unroll
          for (int n = 0; n < 4; ++n)
#pragma unroll
            for (int j = 0; j < 4; ++j) {
              float s = sacc[r2][n][j];
              if (diag && (kt * 64 + n * 16 + fq * 4 + j) > qg) s = -__builtin_inff();
              sv[n][j] = s;
            }
          float pmax = sv[0][0];
#pragma unroll
          for (int n = 0; n < 4; ++n)
#pragma unroll
            for (int j = 0; j < 4; ++j) pmax = fmaxf(pmax, sv[n][j]);
          pmax = fmaxf(pmax, __shfl_xor(pmax, 16, 64));
          pmax = fmaxf(pmax, __shfl_xor(pmax, 32, 64));

          const bool nof = __all(pmax <= m_[r2] + 8.f);
          const float mn = nof ? m_[r2] : fmaxf(m_[r2], pmax);
          float ps = 0.f;
#pragma unroll
          for (int n = 0; n < 4; ++n) {
            union { __hip_bfloat16 hh[4]; uint2 u; } pkk;
#pragma unroll
            for (int j = 0; j < 4; ++j) {
              float p = __expf(sv[n][j] - mn);
              ps += p;
              pkk.hh[j] = __float2bfloat16(p);
            }
            *(uint2*)&Psw[(r2 * 16 + fr) * 72 + n * 16 + fq * 4] = pkk.u;
          }
          ps += __shfl_xor(ps, 16, 64);
          ps += __shfl_xor(ps, 32, 64);

          if (!nof) {
            const float alpha = __expf(m_[r2] - mn);
            l_[r2] = l_[r2] * alpha + ps;
            m_[r2] = mn;
            float a0 = __shfl(alpha, fq * 4 + 0, 64);
            float a1 = __shfl(alpha, fq * 4 + 1, 64);
            float a2 = __shfl(alpha, fq * 4 + 2, 64);
            float a3 = __shfl(alpha, fq * 4 + 3, 64);
#pragma unroll
            for (int nd = 0; nd < 8; ++nd) {
              oacc[r2][nd][0] *= a0; oacc[r2][nd][1] *= a1;
              oacc[r2][nd][2] *= a2; oacc[r2][nd][3] *= a3;
            }
          } else {
            l_[r2] += ps;
          }
        }

#pragma unroll
        for (int kk2 = 0; kk2 < 2; ++kk2) {
          bf16x8 pa0 = *(const bf16x8*)&Psw[(0 * 16 + fr) * 72 + kk2 * 32 + fq * 8];
          bf16x8 pa1 = *(const bf16x8*)&Psw[(1 * 16 + fr) * 72 + kk2 * 32 + fq * 8];
#pragma unroll
          for (int nd = 0; nd < 8; ++nd) {
            bf16x8 vf = *(const bf16x8*)&Vts[(nd * 16 + fr) * 64 + (((kk2 * 4 + fq) ^ (fr & 7)) * 8)];
            oacc[0][nd] = __builtin_amdgcn_mfma_f32_16x16x32_bf16(pa0, vf, oacc[0][nd], 0, 0, 0);
            oacc[1][nd] = __builtin_amdgcn_mfma_f32_16x16x32_bf16(pa1, vf, oacc[1][nd], 0, 0, 0);
          }
        }
      }

      __syncthreads();
      cur ^= 1;
    }

    float i0 = 1.0f / l_[0], i1 = 1.0f / l_[1];
    float inv4[2][4];
#pragma unroll
    for (int j = 0; j < 4; ++j) {
      inv4[0][j] = __shfl(i0, fq * 4 + j, 64);
      inv4[1][j] = __shfl(i1, fq * 4 + j, 64);
    }
#pragma unroll
    for (int r2 = 0; r2 < 2; ++r2)
#pragma unroll
      for (int nd = 0; nd < 8; ++nd)
#pragma unroll
        for (int j = 0; j < 4; ++j)
          Os[(w * 32 + r2 * 16 + fq * 4 + j) * 136 + nd * 16 + fr] =
              __float2bfloat16(oacc[r2][nd][j] * inv4[r2][j]);
    __syncthreads();
#pragma unroll
    for (int it = 0; it < 8; ++it) {
      int i = it * 256 + tid;
      int row = i >> 4, ch = i & 15;
      *(bf16x8*)&O[(size_t)(b * PS + q0 + row) * PE + h * 128 + ch * 8] =
          *(const bf16x8*)&Os[row * 136 + ch * 8];
    }
  }
}

// ---------------------------------------------------------------------------
extern "C" void kernel_launch(void* const* d_in, const int* in_sizes, int n_in,
                              void* d_out, int out_size, void* d_ws, size_t ws_size,
                              hipStream_t stream) {
  const float* x     = (const float*)d_in[0];
  const float* Wqkvh = (const float*)d_in[1];
  const float* Wout  = (const float*)d_in[2];
  float* out = (float*)d_out;

  char* wsb = (char*)d_ws;
  __hip_bfloat16* proj = (__hip_bfloat16*)wsb;          // [4096][6144] bf16
  wsb += (size_t)PM * PQKV * 2;
  __hip_bfloat16* xb = (__hip_bfloat16*)wsb;            // reused as attn out
  wsb += (size_t)PM * PE * 2;
  __hip_bfloat16* Wq_t = (__hip_bfloat16*)wsb;
  wsb += (size_t)PQKV * PE * 2;
  __hip_bfloat16* Wout_t = (__hip_bfloat16*)wsb;
  wsb += (size_t)PE * PE * 2;
  __hip_bfloat16* Vtp = (__hip_bfloat16*)wsb;           // [32][128][2048]
  wsb += (size_t)PB * PH * PD * PS * 2;
  float* hgbuf = (float*)wsb;
  wsb += (size_t)PB * PH * PS * 4;
  float* csum = (float*)wsb;

  // 0) casts / weight transposes
  cast_f32_bf16<<<(PM * PE / 4 + 255) / 256, 256, 0, stream>>>(x, xb, PM * PE / 4);
  transpose_cast<<<dim3(PQKV / 32, PE / 32), 256, 0, stream>>>(Wqkvh, Wq_t, PN_PROJ, PE, 0);
  transpose_cast<<<dim3(PE / 32, PE / 32), 256, 0, stream>>>(Wout, Wout_t, PE, PE, 0);

  // 1) proj = x @ W_qkvh[:, :6144]  (bf16 out) — 256² counted-vmcnt GEMM
  gemm_8p<256, 256, 2, 4, __hip_bfloat16><<<dim3((PQKV / 256) * (PM / 256)), 512, 0, stream>>>(
      xb, Wq_t, proj, PE, PE, PE, PQKV, PQKV / 256);

  // 2) gate head + causal weighted cumsum (bf16 in place, pre-scaled)
  hg_from_x<<<PM, 256, 0, stream>>>(x, Wqkvh, hgbuf);
  kc_pass1<<<PB * PH * 16, 128, 0, stream>>>(proj, hgbuf, csum);
  kc_pass2<<<PB * PH * 16, 128, 0, stream>>>(proj, hgbuf, csum);

  // 3) V^T pack + MFMA flash attention -> xb
  vt_pack<<<PB * PH * 32, 256, 0, stream>>>(proj, Vtp);
  __hip_bfloat16* Ob = xb;
  attn_mfma<<<PB * PH * 8, 256, 0, stream>>>(proj, Vtp, Ob);

  // 4) out = Oattn @ W_out (fp32 out) — 128x256 tile => 256 blocks (full GPU)
  gemm_8p<128, 256, 1, 8, float><<<dim3((PE / 256) * (PM / 128)), 512, 0, stream>>>(
      Ob, Wout_t, out, PE, PE, PE, PE, PE / 256);
}

// Round 8
// 336.296 us; speedup vs baseline: 9.9113x; 1.0358x over previous
//
#include <hip/hip_runtime.h>
#include <hip/hip_bf16.h>
#include <math.h>

// Problem constants: B=2, S=2048, E=2048, HEADS=16, d=128
#define PB 2
#define PS 2048
#define PE 2048
#define PH 16
#define PD 128
#define PN_PROJ 6160   // 3*E + HEADS (fp32 weight layout)
#define PM 4096        // B*S
#define PQKV 6144      // 3*E — bf16 proj row length

typedef __attribute__((ext_vector_type(8))) short bf16x8;
typedef __attribute__((ext_vector_type(4))) float f32x4;

__device__ __forceinline__ void gload_lds16(const void* g, void* l) {
  __builtin_amdgcn_global_load_lds((const __attribute__((address_space(1))) void*)g,
                                   (__attribute__((address_space(3))) void*)l, 16, 0, 0);
}

// ---------------------------------------------------------------------------
// Chunk-scheduled bf16 MFMA GEMM (m201-style fine interleave).
// C[M,N] = A[M,K](bf16 rm) @ Bt[N,K](bf16 rm).
// K split into 32-wide chunks; 4 LDS slots (4x(BM+BN)x32 bf16); per phase:
// { vmcnt(6); barrier; 8x ds_read_b128 (frags of chunk u); stage chunk u+3
//   (3x global_load_lds/thread); lgkmcnt(0); sched_barrier; setprio(1);
//   16 MFMA; setprio(0) }  — vmcnt counts 2 chunks in flight, never 0 until
// the 2-chunk tail. XOR chunk swizzle (c ^= row&3): pre-swizzled global
// source + swizzled ds_read, linear LDS dest (global_load_lds constraint).
// 8 waves (WM x WN), wave tile (BM/WM) x (BN/WN) = 64x64 -> 16 MFMA/chunk.
// ---------------------------------------------------------------------------
template <int BM, int BN, int WM, int WN, typename OutT>
__global__ __launch_bounds__(512, 1) void gemm_cs(
    const __hip_bfloat16* __restrict__ A, const __hip_bfloat16* __restrict__ Bt,
    OutT* __restrict__ C, int K, int lda, int ldb, int ldc, int nTilesX) {
  constexpr int MF = BM / WM / 16;
  constexpr int NF = BN / WN / 16;
  static_assert(MF * NF == 16, "one 16-MFMA phase per chunk");
  constexpr int SBE = (BM + BN) * 32;   // slot elements
  constexpr int AL = BM / 128;          // A stage rounds per chunk (512thr x 16B)
  constexpr int BL = BN / 128;

  __shared__ __align__(16) __hip_bfloat16 lds[4 * SBE];

  const int tid = threadIdx.x;
  const int w = tid >> 6, lane = tid & 63;
  const int fq = lane >> 4, fr = lane & 15;
  const int wm = w / WN, wn = w % WN;

  // bijective XCD swizzle (gridDim.x % 8 == 0)
  const int total = gridDim.x;
  const int swz = (blockIdx.x & 7) * (total >> 3) + (blockIdx.x >> 3);
  const int mBase = (swz / nTilesX) * BM;
  const int nBase = (swz % nTilesX) * BN;

  const int srow = tid >> 2, sc = tid & 3;  // staging row/chunk-within-row

  auto stage_chunk = [&](int u) {
    char* base = (char*)lds + (size_t)(u & 3) * SBE * 2;
#pragma unroll
    for (int l = 0; l < AL; ++l) {
      int row = l * 128 + srow;
      int cs = sc ^ (row & 3);
      gload_lds16(A + (size_t)(mBase + row) * lda + u * 32 + cs * 8,
                  base + l * 8192 + w * 1024);
    }
#pragma unroll
    for (int l = 0; l < BL; ++l) {
      int row = l * 128 + srow;
      int cs = sc ^ (row & 3);
      gload_lds16(Bt + (size_t)(nBase + row) * ldb + u * 32 + cs * 8,
                  base + BM * 64 + l * 8192 + w * 1024);
    }
  };

  f32x4 acc[MF][NF];
#pragma unroll
  for (int m = 0; m < MF; ++m)
#pragma unroll
    for (int n = 0; n < NF; ++n) acc[m][n] = (f32x4){0.f, 0.f, 0.f, 0.f};

  const int NC = K / 32;
  stage_chunk(0); stage_chunk(1); stage_chunk(2);

#pragma unroll 1
  for (int u = 0; u < NC - 2; ++u) {
    asm volatile("s_waitcnt vmcnt(6)" ::: "memory");   // chunk u landed; u+1,u+2 in flight
    __builtin_amdgcn_s_barrier();
    __builtin_amdgcn_sched_barrier(0);
    const __hip_bfloat16* sl = lds + (size_t)(u & 3) * SBE;
    bf16x8 av[MF], bv[NF];
#pragma unroll
    for (int m = 0; m < MF; ++m) {
      int row = wm * (BM / WM) + m * 16 + fr;
      av[m] = *(const bf16x8*)&sl[row * 32 + ((fq ^ (row & 3)) * 8)];
    }
#pragma unroll
    for (int n = 0; n < NF; ++n) {
      int row = wn * (BN / WN) + n * 16 + fr;
      bv[n] = *(const bf16x8*)&sl[BM * 32 + row * 32 + ((fq ^ (row & 3)) * 8)];
    }
    if (u + 3 < NC) stage_chunk(u + 3);  // slot (u-1)&3, freed; published by top barrier
    asm volatile("s_waitcnt lgkmcnt(0)" ::: "memory");
    __builtin_amdgcn_sched_barrier(0);
    __builtin_amdgcn_s_setprio(1);
#pragma unroll
    for (int m = 0; m < MF; ++m)
#pragma unroll
      for (int n = 0; n < NF; ++n)
        acc[m][n] = __builtin_amdgcn_mfma_f32_16x16x32_bf16(av[m], bv[n], acc[m][n], 0, 0, 0);
    __builtin_amdgcn_s_setprio(0);
  }

  // tail: last 2 chunks, everything already staged
  asm volatile("s_waitcnt vmcnt(0)" ::: "memory");
  __builtin_amdgcn_s_barrier();
#pragma unroll 1
  for (int u = NC - 2; u < NC; ++u) {
    const __hip_bfloat16* sl = lds + (size_t)(u & 3) * SBE;
    bf16x8 av[MF], bv[NF];
#pragma unroll
    for (int m = 0; m < MF; ++m) {
      int row = wm * (BM / WM) + m * 16 + fr;
      av[m] = *(const bf16x8*)&sl[row * 32 + ((fq ^ (row & 3)) * 8)];
    }
#pragma unroll
    for (int n = 0; n < NF; ++n) {
      int row = wn * (BN / WN) + n * 16 + fr;
      bv[n] = *(const bf16x8*)&sl[BM * 32 + row * 32 + ((fq ^ (row & 3)) * 8)];
    }
#pragma unroll
    for (int m = 0; m < MF; ++m)
#pragma unroll
      for (int n = 0; n < NF; ++n)
        acc[m][n] = __builtin_amdgcn_mfma_f32_16x16x32_bf16(av[m], bv[n], acc[m][n], 0, 0, 0);
  }

  // epilogue: C/D layout col=lane&15, row=(lane>>4)*4+reg (m89-verified)
#pragma unroll
  for (int m = 0; m < MF; ++m) {
#pragma unroll
    for (int n = 0; n < NF; ++n) {
      int row0 = mBase + wm * (BM / WM) + m * 16 + fq * 4;
      int col = nBase + wn * (BN / WN) + n * 16 + fr;
#pragma unroll
      for (int j = 0; j < 4; ++j) {
        if constexpr (__is_same(OutT, float))
          C[(size_t)(row0 + j) * ldc + col] = acc[m][n][j];
        else
          C[(size_t)(row0 + j) * ldc + col] = __float2bfloat16(acc[m][n][j]);
      }
    }
  }
}

// ---------------------------------------------------------------------------
__global__ __launch_bounds__(256) void cast_f32_bf16(const float* __restrict__ in,
                                                     __hip_bfloat16* __restrict__ out,
                                                     int n4) {
  int i = blockIdx.x * 256 + threadIdx.x;
  if (i >= n4) return;
  float4 v = ((const float4*)in)[i];
  union { __hip_bfloat16 h[4]; uint2 u; } pk;
  pk.h[0] = __float2bfloat16(v.x); pk.h[1] = __float2bfloat16(v.y);
  pk.h[2] = __float2bfloat16(v.z); pk.h[3] = __float2bfloat16(v.w);
  ((uint2*)out)[i] = pk.u;
}

// ---------------------------------------------------------------------------
__global__ __launch_bounds__(256) void transpose_cast(const float* __restrict__ W,
                                                      __hip_bfloat16* __restrict__ Wt,
                                                      int ldw, int ldt, int nOff) {
  __shared__ float t[32][33];
  int nb = blockIdx.x * 32, kb = blockIdx.y * 32;
  int tx = threadIdx.x & 31, ty = threadIdx.x >> 5;
#pragma unroll
  for (int i = 0; i < 4; ++i) {
    int k = ty + i * 8;
    t[k][tx] = W[(size_t)(kb + k) * ldw + nOff + nb + tx];
  }
  __syncthreads();
#pragma unroll
  for (int i = 0; i < 4; ++i) {
    int n = ty + i * 8;
    Wt[(size_t)(nb + n) * ldt + kb + tx] = __float2bfloat16(t[tx][n]);
  }
}

// ---------------------------------------------------------------------------
// Gate head from x (fp32): hgbuf[(b*H+h)*S+s] = tanh(x[bs,:] . W[:,3E+h])
// ---------------------------------------------------------------------------
__global__ __launch_bounds__(256) void hg_from_x(const float* __restrict__ x,
                                                 const float* __restrict__ W,
                                                 float* __restrict__ hgbuf) {
  int bs = blockIdx.x;
  int b = bs >> 11, s = bs & (PS - 1);
  __shared__ float xs[PE];
  __shared__ float red[16][17];
  const float* xr = x + (size_t)bs * PE;
  for (int i = threadIdx.x; i < PE / 4; i += 256)
    *(float4*)&xs[i * 4] = ((const float4*)xr)[i];
  __syncthreads();
  int h = threadIdx.x & 15, part = threadIdx.x >> 4;
  float acc = 0.f;
  for (int k = part * 128; k < part * 128 + 128; ++k)
    acc += xs[k] * W[(size_t)k * PN_PROJ + 3 * PE + h];
  red[part][h] = acc;
  __syncthreads();
  if (threadIdx.x < 16) {
    float sm = 0.f;
#pragma unroll
    for (int p = 0; p < 16; ++p) sm += red[p][threadIdx.x];
    hgbuf[(size_t)(b * PH + threadIdx.x) * PS + s] = tanhf(sm);
  }
}

// ---------------------------------------------------------------------------
// Kc scan on bf16 proj (fp32 accumulation), pre-scaled by 1/sqrt(E).
// ---------------------------------------------------------------------------
#define KC_SCALE 0.022097086912079608f  // 1/sqrt(2048)

__global__ __launch_bounds__(128) void kc_pass1(const __hip_bfloat16* __restrict__ proj,
                                                const float* __restrict__ hgbuf,
                                                float* __restrict__ csum) {
  int c = blockIdx.x & 15, bh = blockIdx.x >> 4;
  int h = bh & (PH - 1), b = bh >> 4;
  int d = threadIdx.x;
  __shared__ float hgs[128];
  hgs[d] = hgbuf[bh * PS + c * 128 + d];
  __syncthreads();
  const __hip_bfloat16* kbase = proj + (size_t)(b * PS) * PQKV + h * 384 + 128 + d;
  float acc = 0.f;
  int j0 = c * 128;
  for (int i = 0; i < 128; ++i) {
    int j = j0 + i;
    acc += (float)(j + 1) * hgs[i] * __bfloat162float(kbase[(size_t)j * PQKV]);
  }
  csum[blockIdx.x * 128 + d] = acc;
}

__global__ __launch_bounds__(128) void kc_pass2(__hip_bfloat16* __restrict__ proj,
                                                const float* __restrict__ hgbuf,
                                                const float* __restrict__ csum) {
  int c = blockIdx.x & 15, bh = blockIdx.x >> 4;
  int h = bh & (PH - 1), b = bh >> 4;
  int d = threadIdx.x;
  __shared__ float hgs[128];
  hgs[d] = hgbuf[bh * PS + c * 128 + d];
  __syncthreads();
  float acc = 0.f;
  for (int cc = 0; cc < c; ++cc) acc += csum[(bh * 16 + cc) * 128 + d];
  __hip_bfloat16* kbase = proj + (size_t)(b * PS) * PQKV + h * 384 + 128 + d;
  int j0 = c * 128;
  for (int i = 0; i < 128; ++i) {
    int j = j0 + i;
    acc += (float)(j + 1) * hgs[i] * __bfloat162float(kbase[(size_t)j * PQKV]);
    float t = (float)(j + 1);
    kbase[(size_t)j * PQKV] = __float2bfloat16(acc / (t * t) * KC_SCALE);
  }
}

// ---------------------------------------------------------------------------
// V^T pack: Vtp[bh][d][s]
// ---------------------------------------------------------------------------
__global__ __launch_bounds__(256) void vt_pack(const __hip_bfloat16* __restrict__ proj,
                                               __hip_bfloat16* __restrict__ Vtp) {
  int sc = blockIdx.x & 31, bh = blockIdx.x >> 5;
  int b = bh >> 4, h = bh & 15;
  int s0 = sc * 64;
  int tid = threadIdx.x;
  __shared__ __align__(16) __hip_bfloat16 Vlds[64][136];
  const __hip_bfloat16* src = proj + (size_t)(b * PS + s0) * PQKV + h * 384 + 256;
#pragma unroll
  for (int it = 0; it < 4; ++it) {
    int i = it * 256 + tid;
    int row = i >> 4, ch = i & 15;
    *(bf16x8*)&Vlds[row][ch * 8] = *(const bf16x8*)&src[(size_t)row * PQKV + ch * 8];
  }
  __syncthreads();
  int d = tid >> 1, half = tid & 1;
  __hip_bfloat16* dst = Vtp + ((size_t)bh * 128 + d) * PS + s0 + half * 32;
#pragma unroll
  for (int c8 = 0; c8 < 8; ++c8) {
    union { __hip_bfloat16 h4[4]; uint2 u; } pk;
#pragma unroll
    for (int k = 0; k < 4; ++k) pk.h4[k] = Vlds[half * 32 + c8 * 4 + k][d];
    *(uint2*)&dst[c8 * 4] = pk.u;
  }
}

// ---------------------------------------------------------------------------
// MFMA flash attention v3 (validated in R6/R7): causal-balanced pairing,
// dbuf KV staging, swapped QK^T, defer-max, XOR-swizzled LDS.
// ---------------------------------------------------------------------------
__global__ __launch_bounds__(256) void attn_mfma(const __hip_bfloat16* __restrict__ proj,
                                                 const __hip_bfloat16* __restrict__ Vtp,
                                                 __hip_bfloat16* __restrict__ O) {
  const int bid = (blockIdx.x & 7) * 32 + (blockIdx.x >> 3);
  const int bh = bid >> 3, pk = bid & 7;
  const int b = bh >> 4, h = bh & 15;
  const int tid = threadIdx.x;
  const int w = tid >> 6, lane = tid & 63;
  const int fq = lane >> 4, fr = lane & 15;

  __shared__ __align__(16) char smem[120832];
  __hip_bfloat16* Psw = (__hip_bfloat16*)(smem + 65536) + w * 32 * 72;
  __hip_bfloat16* Os = (__hip_bfloat16*)(smem + 84480);

  const __hip_bfloat16* kb0 = proj + (size_t)(b * PS) * PQKV + h * 384 + 128;
  const __hip_bfloat16* vb0 = Vtp + (size_t)bh * 128 * PS;

  const int klr = lane >> 4, kc = lane & 15;
  const int vlr = lane >> 3, vc = lane & 7;

  auto stageKV = [&](int t, int bufi) {
    char* ksb = smem + bufi * 16384;
    char* vsb = smem + 32768 + bufi * 16384;
    const __hip_bfloat16* kb = kb0 + (size_t)(t * 64) * PQKV;
    const __hip_bfloat16* vb = vb0 + t * 64;
#pragma unroll
    for (int p = 0; p < 4; ++p) {
      int row = w * 16 + p * 4 + klr;
      int cs = kc ^ (row & 7);
      gload_lds16(kb + (size_t)row * PQKV + cs * 8, ksb + (w * 16 + p * 4) * 256);
    }
#pragma unroll
    for (int p = 0; p < 4; ++p) {
      int row = w * 32 + p * 8 + vlr;
      int cs = vc ^ (row & 7);
      gload_lds16(vb + (size_t)row * PS + cs * 8, vsb + (w * 32 + p * 8) * 128);
    }
  };

  stageKV(0, 0);
  int cur = 0;

#pragma unroll 1
  for (int phase = 0; phase < 2; ++phase) {
    const int qt = (phase == 0) ? pk : 15 - pk;
    const int nt = (qt + 1) * 2;
    const int q0 = qt * 128;
    const int qw = q0 + w * 32;

    const __hip_bfloat16* qbase = proj + (size_t)(b * PS + qw) * PQKV + h * 384;
    bf16x8 qf[2][4];
#pragma unroll
    for (int r2 = 0; r2 < 2; ++r2)
#pragma unroll
      for (int kk = 0; kk < 4; ++kk)
        qf[r2][kk] = *(const bf16x8*)&qbase[(size_t)(r2 * 16 + fr) * PQKV + kk * 32 + fq * 8];

    f32x4 oacc[2][8];
#pragma unroll
    for (int r2 = 0; r2 < 2; ++r2)
#pragma unroll
      for (int nd = 0; nd < 8; ++nd) oacc[r2][nd] = (f32x4){0.f, 0.f, 0.f, 0.f};
    float m_[2] = {-__builtin_inff(), -__builtin_inff()};
    float l_[2] = {0.f, 0.f};

#pragma unroll 1
    for (int kt = 0; kt < nt; ++kt) {
      const bool hasNext = (kt + 1 < nt) || (phase == 0);
      if (hasNext) stageKV((kt + 1 < nt) ? kt + 1 : 0, cur ^ 1);

      if (kt * 64 <= qw + 31) {
        const __hip_bfloat16* Ks = (const __hip_bfloat16*)(smem + cur * 16384);
        const __hip_bfloat16* Vts = (const __hip_bfloat16*)(smem + 32768 + cur * 16384);
        const bool diag = (kt * 64 + 63) > qw;

        f32x4 sacc[2][4];
#pragma unroll
        for (int r2 = 0; r2 < 2; ++r2)
#pragma unroll
          for (int n = 0; n < 4; ++n) sacc[r2][n] = (f32x4){0.f, 0.f, 0.f, 0.f};
#pragma unroll
        for (int kk = 0; kk < 4; ++kk) {
#pragma unroll
          for (int n = 0; n < 4; ++n) {
            bf16x8 kf = *(const bf16x8*)&Ks[(n * 16 + fr) * 128 + (((kk * 4 + fq) ^ (fr & 7)) * 8)];
            sacc[0][n] = __builtin_amdgcn_mfma_f32_16x16x32_bf16(kf, qf[0][kk], sacc[0][n], 0, 0, 0);
            sacc[1][n] = __builtin_amdgcn_mfma_f32_16x16x32_bf16(kf, qf[1][kk], sacc[1][n], 0, 0, 0);
          }
        }

#pragma unroll
        for (int r2 = 0; r2 < 2; ++r2) {
          const int qg = qw + r2 * 16 + fr;
          float sv[4][4];
#pragma unroll
          for (int n = 0; n < 4; ++n)
#pragma unroll
            for (int j = 0; j < 4; ++j) {
              float s = sacc[r2][n][j];
              if (diag && (kt * 64 + n * 16 + fq * 4 + j) > qg) s = -__builtin_inff();
              sv[n][j] = s;
            }
          float pmax = sv[0][0];
#pragma unroll
          for (int n = 0; n < 4; ++n)
#pragma unroll
            for (int j = 0; j < 4; ++j) pmax = fmaxf(pmax, sv[n][j]);
          pmax = fmaxf(pmax, __shfl_xor(pmax, 16, 64));
          pmax = fmaxf(pmax, __shfl_xor(pmax, 32, 64));

          const bool nof = __all(pmax <= m_[r2] + 8.f);
          const float mn = nof ? m_[r2] : fmaxf(m_[r2], pmax);
          float ps = 0.f;
#pragma unroll
          for (int n = 0; n < 4; ++n) {
            union { __hip_bfloat16 hh[4]; uint2 u; } pkk;
#pragma unroll
            for (int j = 0; j < 4; ++j) {
              float p = __expf(sv[n][j] - mn);
              ps += p;
              pkk.hh[j] = __float2bfloat16(p);
            }
            *(uint2*)&Psw[(r2 * 16 + fr) * 72 + n * 16 + fq * 4] = pkk.u;
          }
          ps += __shfl_xor(ps, 16, 64);
          ps += __shfl_xor(ps, 32, 64);

          if (!nof) {
            const float alpha = __expf(m_[r2] - mn);
            l_[r2] = l_[r2] * alpha + ps;
            m_[r2] = mn;
            float a0 = __shfl(alpha, fq * 4 + 0, 64);
            float a1 = __shfl(alpha, fq * 4 + 1, 64);
            float a2 = __shfl(alpha, fq * 4 + 2, 64);
            float a3 = __shfl(alpha, fq * 4 + 3, 64);
#pragma unroll
            for (int nd = 0; nd < 8; ++nd) {
              oacc[r2][nd][0] *= a0; oacc[r2][nd][1] *= a1;
              oacc[r2][nd][2] *= a2; oacc[r2][nd][3] *= a3;
            }
          } else {
            l_[r2] += ps;
          }
        }

#pragma unroll
        for (int kk2 = 0; kk2 < 2; ++kk2) {
          bf16x8 pa0 = *(const bf16x8*)&Psw[(0 * 16 + fr) * 72 + kk2 * 32 + fq * 8];
          bf16x8 pa1 = *(const bf16x8*)&Psw[(1 * 16 + fr) * 72 + kk2 * 32 + fq * 8];
#pragma unroll
          for (int nd = 0; nd < 8; ++nd) {
            bf16x8 vf = *(const bf16x8*)&Vts[(nd * 16 + fr) * 64 + (((kk2 * 4 + fq) ^ (fr & 7)) * 8)];
            oacc[0][nd] = __builtin_amdgcn_mfma_f32_16x16x32_bf16(pa0, vf, oacc[0][nd], 0, 0, 0);
            oacc[1][nd] = __builtin_amdgcn_mfma_f32_16x16x32_bf16(pa1, vf, oacc[1][nd], 0, 0, 0);
          }
        }
      }

      __syncthreads();
      cur ^= 1;
    }

    float i0 = 1.0f / l_[0], i1 = 1.0f / l_[1];
    float inv4[2][4];
#pragma unroll
    for (int j = 0; j < 4; ++j) {
      inv4[0][j] = __shfl(i0, fq * 4 + j, 64);
      inv4[1][j] = __shfl(i1, fq * 4 + j, 64);
    }
#pragma unroll
    for (int r2 = 0; r2 < 2; ++r2)
#pragma unroll
      for (int nd = 0; nd < 8; ++nd)
#pragma unroll
        for (int j = 0; j < 4; ++j)
          Os[(w * 32 + r2 * 16 + fq * 4 + j) * 136 + nd * 16 + fr] =
              __float2bfloat16(oacc[r2][nd][j] * inv4[r2][j]);
    __syncthreads();
#pragma unroll
    for (int it = 0; it < 8; ++it) {
      int i = it * 256 + tid;
      int row = i >> 4, ch = i & 15;
      *(bf16x8*)&O[(size_t)(b * PS + q0 + row) * PE + h * 128 + ch * 8] =
          *(const bf16x8*)&Os[row * 136 + ch * 8];
    }
  }
}

// ---------------------------------------------------------------------------
extern "C" void kernel_launch(void* const* d_in, const int* in_sizes, int n_in,
                              void* d_out, int out_size, void* d_ws, size_t ws_size,
                              hipStream_t stream) {
  const float* x     = (const float*)d_in[0];
  const float* Wqkvh = (const float*)d_in[1];
  const float* Wout  = (const float*)d_in[2];
  float* out = (float*)d_out;

  char* wsb = (char*)d_ws;
  __hip_bfloat16* proj = (__hip_bfloat16*)wsb;          // [4096][6144] bf16
  wsb += (size_t)PM * PQKV * 2;
  __hip_bfloat16* xb = (__hip_bfloat16*)wsb;            // reused as attn out
  wsb += (size_t)PM * PE * 2;
  __hip_bfloat16* Wq_t = (__hip_bfloat16*)wsb;
  wsb += (size_t)PQKV * PE * 2;
  __hip_bfloat16* Wout_t = (__hip_bfloat16*)wsb;
  wsb += (size_t)PE * PE * 2;
  __hip_bfloat16* Vtp = (__hip_bfloat16*)wsb;           // [32][128][2048]
  wsb += (size_t)PB * PH * PD * PS * 2;
  float* hgbuf = (float*)wsb;
  wsb += (size_t)PB * PH * PS * 4;
  float* csum = (float*)wsb;

  // 0) casts / weight transposes
  cast_f32_bf16<<<(PM * PE / 4 + 255) / 256, 256, 0, stream>>>(x, xb, PM * PE / 4);
  transpose_cast<<<dim3(PQKV / 32, PE / 32), 256, 0, stream>>>(Wqkvh, Wq_t, PN_PROJ, PE, 0);
  transpose_cast<<<dim3(PE / 32, PE / 32), 256, 0, stream>>>(Wout, Wout_t, PE, PE, 0);

  // 1) proj = x @ W_qkvh[:, :6144] (bf16 out) — chunk-scheduled GEMM,
  //    grid 768 = 3 exact rounds of 256 CUs
  gemm_cs<128, 256, 2, 4, __hip_bfloat16>
      <<<dim3((PM / 128) * (PQKV / 256)), 512, 0, stream>>>(
          xb, Wq_t, proj, PE, PE, PE, PQKV, PQKV / 256);

  // 2) gate head + causal weighted cumsum (bf16 in place, pre-scaled)
  hg_from_x<<<PM, 256, 0, stream>>>(x, Wqkvh, hgbuf);
  kc_pass1<<<PB * PH * 16, 128, 0, stream>>>(proj, hgbuf, csum);
  kc_pass2<<<PB * PH * 16, 128, 0, stream>>>(proj, hgbuf, csum);

  // 3) V^T pack + MFMA flash attention -> xb
  vt_pack<<<PB * PH * 32, 256, 0, stream>>>(proj, Vtp);
  __hip_bfloat16* Ob = xb;
  attn_mfma<<<PB * PH * 8, 256, 0, stream>>>(proj, Vtp, Ob);

  // 4) out = Oattn @ W_out (fp32 out) — grid 256 = 1 exact round
  gemm_cs<128, 256, 2, 4, float>
      <<<dim3((PM / 128) * (PE / 256)), 512, 0, stream>>>(
          Ob, Wout_t, out, PE, PE, PE, PE, PE / 256);
}

// Round 9
// 319.944 us; speedup vs baseline: 10.4178x; 1.0511x over previous
//
#include <hip/hip_runtime.h>
#include <hip/hip_bf16.h>
#include <math.h>

// Problem constants: B=2, S=2048, E=2048, HEADS=16, d=128
#define PB 2
#define PS 2048
#define PE 2048
#define PH 16
#define PD 128
#define PN_PROJ 6160   // 3*E + HEADS (fp32 weight layout)
#define PM 4096        // B*S
#define PQKV 6144      // 3*E — bf16 proj row length

typedef __attribute__((ext_vector_type(8))) short bf16x8;
typedef __attribute__((ext_vector_type(4))) float f32x4;

__device__ __forceinline__ void gload_lds16(const void* g, void* l) {
  __builtin_amdgcn_global_load_lds((const __attribute__((address_space(1))) void*)g,
                                   (__attribute__((address_space(3))) void*)l, 16, 0, 0);
}

// ---------------------------------------------------------------------------
// BK=64 counted-vmcnt bf16 MFMA GEMM.
// C[M,N] = A[M,K](bf16 rm) @ Bt[N,K](bf16 rm).
// 2 LDS slots of (BM+BN)x64 bf16; 128B rows -> 8-position XOR swizzle
// (c ^= row&7): conflict-free ds_read_b128 (residual 2-way = free).
// Per K-tile: vmcnt(NLD); barrier; {ds_read kk0; lgkm; MFMA kk0};
// {ds_read kk1; lgkm; barrier; stage(t+2) into freed slot; MFMA kk1}.
// vmcnt never 0 until the tail (1 future tile always in flight).
// 8 waves WM x WN; wave tile (BM/WM) x (BN/WN).
// ---------------------------------------------------------------------------
template <int BM, int BN, int WM, int WN, typename OutT>
__global__ __launch_bounds__(512, 1) void gemm_cs2(
    const __hip_bfloat16* __restrict__ A, const __hip_bfloat16* __restrict__ Bt,
    OutT* __restrict__ C, int K, int lda, int ldb, int ldc, int nTilesX) {
  constexpr int MF = BM / WM / 16;
  constexpr int NF = BN / WN / 16;
  constexpr int SLOT = (BM + BN) * 64;      // elements per slot
  constexpr int AL = BM / 64;               // A stage rounds (64 rows/round)
  constexpr int BL = BN / 64;
  constexpr int NLD = AL + BL;              // gload_lds per thread per K-tile

  __shared__ __align__(16) __hip_bfloat16 lds[2 * SLOT];

  const int tid = threadIdx.x;
  const int w = tid >> 6, lane = tid & 63;
  const int fq = lane >> 4, fr = lane & 15;
  const int wm = w / WN, wn = w % WN;

  // bijective XCD swizzle (gridDim.x % 8 == 0)
  const int total = gridDim.x;
  const int swz = (blockIdx.x & 7) * (total >> 3) + (blockIdx.x >> 3);
  const int mBase = (swz / nTilesX) * BM;
  const int nBase = (swz % nTilesX) * BN;

  const int srow = tid >> 3, sc = tid & 7;  // staging: 64 rows x 8 chunks / round

  auto stage = [&](int t) {
    char* base = (char*)lds + (size_t)(t & 1) * SLOT * 2;
#pragma unroll
    for (int l = 0; l < AL; ++l) {
      int row = l * 64 + srow;
      int cs = sc ^ (row & 7);
      gload_lds16(A + (size_t)(mBase + row) * lda + t * 64 + cs * 8,
                  base + l * 8192 + w * 1024);
    }
#pragma unroll
    for (int l = 0; l < BL; ++l) {
      int row = l * 64 + srow;
      int cs = sc ^ (row & 7);
      gload_lds16(Bt + (size_t)(nBase + row) * ldb + t * 64 + cs * 8,
                  base + BM * 128 + l * 8192 + w * 1024);
    }
  };

  f32x4 acc[MF][NF];
#pragma unroll
  for (int m = 0; m < MF; ++m)
#pragma unroll
    for (int n = 0; n < NF; ++n) acc[m][n] = (f32x4){0.f, 0.f, 0.f, 0.f};

  const int NT = K / 64;
  stage(0); stage(1);

#pragma unroll 1
  for (int t = 0; t < NT; ++t) {
    if (t + 1 < NT) asm volatile("s_waitcnt vmcnt(%0)" ::"i"(NLD) : "memory");
    else            asm volatile("s_waitcnt vmcnt(0)" ::: "memory");
    __builtin_amdgcn_s_barrier();       // tile t published to all waves
    __builtin_amdgcn_sched_barrier(0);

    const __hip_bfloat16* sl = lds + (size_t)(t & 1) * SLOT;

    // ---- kk = 0 ----
    bf16x8 av[MF], bv[NF];
#pragma unroll
    for (int m = 0; m < MF; ++m) {
      int row = wm * (BM / WM) + m * 16 + fr;
      av[m] = *(const bf16x8*)&sl[row * 64 + ((fq ^ (row & 7)) * 8)];
    }
#pragma unroll
    for (int n = 0; n < NF; ++n) {
      int row = wn * (BN / WN) + n * 16 + fr;
      bv[n] = *(const bf16x8*)&sl[BM * 64 + row * 64 + ((fq ^ (row & 7)) * 8)];
    }
    asm volatile("s_waitcnt lgkmcnt(0)" ::: "memory");
    __builtin_amdgcn_sched_barrier(0);
    __builtin_amdgcn_s_setprio(1);
#pragma unroll
    for (int m = 0; m < MF; ++m)
#pragma unroll
      for (int n = 0; n < NF; ++n)
        acc[m][n] = __builtin_amdgcn_mfma_f32_16x16x32_bf16(av[m], bv[n], acc[m][n], 0, 0, 0);
    __builtin_amdgcn_s_setprio(0);

    // ---- kk = 1 ----
#pragma unroll
    for (int m = 0; m < MF; ++m) {
      int row = wm * (BM / WM) + m * 16 + fr;
      av[m] = *(const bf16x8*)&sl[row * 64 + (((4 + fq) ^ (row & 7)) * 8)];
    }
#pragma unroll
    for (int n = 0; n < NF; ++n) {
      int row = wn * (BN / WN) + n * 16 + fr;
      bv[n] = *(const bf16x8*)&sl[BM * 64 + row * 64 + (((4 + fq) ^ (row & 7)) * 8)];
    }
    asm volatile("s_waitcnt lgkmcnt(0)" ::: "memory");
    __builtin_amdgcn_s_barrier();       // all waves done reading slot t&1
    __builtin_amdgcn_sched_barrier(0);
    if (t + 2 < NT) stage(t + 2);       // into the just-freed slot
    __builtin_amdgcn_s_setprio(1);
#pragma unroll
    for (int m = 0; m < MF; ++m)
#pragma unroll
      for (int n = 0; n < NF; ++n)
        acc[m][n] = __builtin_amdgcn_mfma_f32_16x16x32_bf16(av[m], bv[n], acc[m][n], 0, 0, 0);
    __builtin_amdgcn_s_setprio(0);
  }

  // epilogue: C/D layout col=lane&15, row=(lane>>4)*4+reg (m89-verified)
#pragma unroll
  for (int m = 0; m < MF; ++m) {
#pragma unroll
    for (int n = 0; n < NF; ++n) {
      int row0 = mBase + wm * (BM / WM) + m * 16 + fq * 4;
      int col = nBase + wn * (BN / WN) + n * 16 + fr;
#pragma unroll
      for (int j = 0; j < 4; ++j) {
        if constexpr (__is_same(OutT, float))
          C[(size_t)(row0 + j) * ldc + col] = acc[m][n][j];
        else
          C[(size_t)(row0 + j) * ldc + col] = __float2bfloat16(acc[m][n][j]);
      }
    }
  }
}

// ---------------------------------------------------------------------------
__global__ __launch_bounds__(256) void cast_f32_bf16(const float* __restrict__ in,
                                                     __hip_bfloat16* __restrict__ out,
                                                     int n4) {
  int i = blockIdx.x * 256 + threadIdx.x;
  if (i >= n4) return;
  float4 v = ((const float4*)in)[i];
  union { __hip_bfloat16 h[4]; uint2 u; } pk;
  pk.h[0] = __float2bfloat16(v.x); pk.h[1] = __float2bfloat16(v.y);
  pk.h[2] = __float2bfloat16(v.z); pk.h[3] = __float2bfloat16(v.w);
  ((uint2*)out)[i] = pk.u;
}

// ---------------------------------------------------------------------------
__global__ __launch_bounds__(256) void transpose_cast(const float* __restrict__ W,
                                                      __hip_bfloat16* __restrict__ Wt,
                                                      int ldw, int ldt, int nOff) {
  __shared__ float t[32][33];
  int nb = blockIdx.x * 32, kb = blockIdx.y * 32;
  int tx = threadIdx.x & 31, ty = threadIdx.x >> 5;
#pragma unroll
  for (int i = 0; i < 4; ++i) {
    int k = ty + i * 8;
    t[k][tx] = W[(size_t)(kb + k) * ldw + nOff + nb + tx];
  }
  __syncthreads();
#pragma unroll
  for (int i = 0; i < 4; ++i) {
    int n = ty + i * 8;
    Wt[(size_t)(nb + n) * ldt + kb + tx] = __float2bfloat16(t[tx][n]);
  }
}

// ---------------------------------------------------------------------------
// Gate head from x (fp32): hgbuf[(b*H+h)*S+s] = tanh(x[bs,:] . W[:,3E+h])
// ---------------------------------------------------------------------------
__global__ __launch_bounds__(256) void hg_from_x(const float* __restrict__ x,
                                                 const float* __restrict__ W,
                                                 float* __restrict__ hgbuf) {
  int bs = blockIdx.x;
  int b = bs >> 11, s = bs & (PS - 1);
  __shared__ float xs[PE];
  __shared__ float red[16][17];
  const float* xr = x + (size_t)bs * PE;
  for (int i = threadIdx.x; i < PE / 4; i += 256)
    *(float4*)&xs[i * 4] = ((const float4*)xr)[i];
  __syncthreads();
  int h = threadIdx.x & 15, part = threadIdx.x >> 4;
  float acc = 0.f;
  for (int k = part * 128; k < part * 128 + 128; ++k)
    acc += xs[k] * W[(size_t)k * PN_PROJ + 3 * PE + h];
  red[part][h] = acc;
  __syncthreads();
  if (threadIdx.x < 16) {
    float sm = 0.f;
#pragma unroll
    for (int p = 0; p < 16; ++p) sm += red[p][threadIdx.x];
    hgbuf[(size_t)(b * PH + threadIdx.x) * PS + s] = tanhf(sm);
  }
}

// ---------------------------------------------------------------------------
// Kc scan on bf16 proj (fp32 accumulation), pre-scaled by 1/sqrt(E).
// ---------------------------------------------------------------------------
#define KC_SCALE 0.022097086912079608f  // 1/sqrt(2048)

__global__ __launch_bounds__(128) void kc_pass1(const __hip_bfloat16* __restrict__ proj,
                                                const float* __restrict__ hgbuf,
                                                float* __restrict__ csum) {
  int c = blockIdx.x & 15, bh = blockIdx.x >> 4;
  int h = bh & (PH - 1), b = bh >> 4;
  int d = threadIdx.x;
  __shared__ float hgs[128];
  hgs[d] = hgbuf[bh * PS + c * 128 + d];
  __syncthreads();
  const __hip_bfloat16* kbase = proj + (size_t)(b * PS) * PQKV + h * 384 + 128 + d;
  float acc = 0.f;
  int j0 = c * 128;
  for (int i = 0; i < 128; ++i) {
    int j = j0 + i;
    acc += (float)(j + 1) * hgs[i] * __bfloat162float(kbase[(size_t)j * PQKV]);
  }
  csum[blockIdx.x * 128 + d] = acc;
}

__global__ __launch_bounds__(128) void kc_pass2(__hip_bfloat16* __restrict__ proj,
                                                const float* __restrict__ hgbuf,
                                                const float* __restrict__ csum) {
  int c = blockIdx.x & 15, bh = blockIdx.x >> 4;
  int h = bh & (PH - 1), b = bh >> 4;
  int d = threadIdx.x;
  __shared__ float hgs[128];
  hgs[d] = hgbuf[bh * PS + c * 128 + d];
  __syncthreads();
  float acc = 0.f;
  for (int cc = 0; cc < c; ++cc) acc += csum[(bh * 16 + cc) * 128 + d];
  __hip_bfloat16* kbase = proj + (size_t)(b * PS) * PQKV + h * 384 + 128 + d;
  int j0 = c * 128;
  for (int i = 0; i < 128; ++i) {
    int j = j0 + i;
    acc += (float)(j + 1) * hgs[i] * __bfloat162float(kbase[(size_t)j * PQKV]);
    float t = (float)(j + 1);
    kbase[(size_t)j * PQKV] = __float2bfloat16(acc / (t * t) * KC_SCALE);
  }
}

// ---------------------------------------------------------------------------
// V^T pack: Vtp[bh][d][s]
// ---------------------------------------------------------------------------
__global__ __launch_bounds__(256) void vt_pack(const __hip_bfloat16* __restrict__ proj,
                                               __hip_bfloat16* __restrict__ Vtp) {
  int sc = blockIdx.x & 31, bh = blockIdx.x >> 5;
  int b = bh >> 4, h = bh & 15;
  int s0 = sc * 64;
  int tid = threadIdx.x;
  __shared__ __align__(16) __hip_bfloat16 Vlds[64][136];
  const __hip_bfloat16* src = proj + (size_t)(b * PS + s0) * PQKV + h * 384 + 256;
#pragma unroll
  for (int it = 0; it < 4; ++it) {
    int i = it * 256 + tid;
    int row = i >> 4, ch = i & 15;
    *(bf16x8*)&Vlds[row][ch * 8] = *(const bf16x8*)&src[(size_t)row * PQKV + ch * 8];
  }
  __syncthreads();
  int d = tid >> 1, half = tid & 1;
  __hip_bfloat16* dst = Vtp + ((size_t)bh * 128 + d) * PS + s0 + half * 32;
#pragma unroll
  for (int c8 = 0; c8 < 8; ++c8) {
    union { __hip_bfloat16 h4[4]; uint2 u; } pk;
#pragma unroll
    for (int k = 0; k < 4; ++k) pk.h4[k] = Vlds[half * 32 + c8 * 4 + k][d];
    *(uint2*)&dst[c8 * 4] = pk.u;
  }
}

// ---------------------------------------------------------------------------
// MFMA flash attention v3 (validated R6-R8): causal-balanced pairing,
// dbuf KV staging, swapped QK^T, defer-max, XOR-swizzled LDS.
// ---------------------------------------------------------------------------
__global__ __launch_bounds__(256) void attn_mfma(const __hip_bfloat16* __restrict__ proj,
                                                 const __hip_bfloat16* __restrict__ Vtp,
                                                 __hip_bfloat16* __restrict__ O) {
  const int bid = (blockIdx.x & 7) * 32 + (blockIdx.x >> 3);
  const int bh = bid >> 3, pk = bid & 7;
  const int b = bh >> 4, h = bh & 15;
  const int tid = threadIdx.x;
  const int w = tid >> 6, lane = tid & 63;
  const int fq = lane >> 4, fr = lane & 15;

  __shared__ __align__(16) char smem[120832];
  __hip_bfloat16* Psw = (__hip_bfloat16*)(smem + 65536) + w * 32 * 72;
  __hip_bfloat16* Os = (__hip_bfloat16*)(smem + 84480);

  const __hip_bfloat16* kb0 = proj + (size_t)(b * PS) * PQKV + h * 384 + 128;
  const __hip_bfloat16* vb0 = Vtp + (size_t)bh * 128 * PS;

  const int klr = lane >> 4, kc = lane & 15;
  const int vlr = lane >> 3, vc = lane & 7;

  auto stageKV = [&](int t, int bufi) {
    char* ksb = smem + bufi * 16384;
    char* vsb = smem + 32768 + bufi * 16384;
    const __hip_bfloat16* kb = kb0 + (size_t)(t * 64) * PQKV;
    const __hip_bfloat16* vb = vb0 + t * 64;
#pragma unroll
    for (int p = 0; p < 4; ++p) {
      int row = w * 16 + p * 4 + klr;
      int cs = kc ^ (row & 7);
      gload_lds16(kb + (size_t)row * PQKV + cs * 8, ksb + (w * 16 + p * 4) * 256);
    }
#pragma unroll
    for (int p = 0; p < 4; ++p) {
      int row = w * 32 + p * 8 + vlr;
      int cs = vc ^ (row & 7);
      gload_lds16(vb + (size_t)row * PS + cs * 8, vsb + (w * 32 + p * 8) * 128);
    }
  };

  stageKV(0, 0);
  int cur = 0;

#pragma unroll 1
  for (int phase = 0; phase < 2; ++phase) {
    const int qt = (phase == 0) ? pk : 15 - pk;
    const int nt = (qt + 1) * 2;
    const int q0 = qt * 128;
    const int qw = q0 + w * 32;

    const __hip_bfloat16* qbase = proj + (size_t)(b * PS + qw) * PQKV + h * 384;
    bf16x8 qf[2][4];
#pragma unroll
    for (int r2 = 0; r2 < 2; ++r2)
#pragma unroll
      for (int kk = 0; kk < 4; ++kk)
        qf[r2][kk] = *(const bf16x8*)&qbase[(size_t)(r2 * 16 + fr) * PQKV + kk * 32 + fq * 8];

    f32x4 oacc[2][8];
#pragma unroll
    for (int r2 = 0; r2 < 2; ++r2)
#pragma unroll
      for (int nd = 0; nd < 8; ++nd) oacc[r2][nd] = (f32x4){0.f, 0.f, 0.f, 0.f};
    float m_[2] = {-__builtin_inff(), -__builtin_inff()};
    float l_[2] = {0.f, 0.f};

#pragma unroll 1
    for (int kt = 0; kt < nt; ++kt) {
      const bool hasNext = (kt + 1 < nt) || (phase == 0);
      if (hasNext) stageKV((kt + 1 < nt) ? kt + 1 : 0, cur ^ 1);

      if (kt * 64 <= qw + 31) {
        const __hip_bfloat16* Ks = (const __hip_bfloat16*)(smem + cur * 16384);
        const __hip_bfloat16* Vts = (const __hip_bfloat16*)(smem + 32768 + cur * 16384);
        const bool diag = (kt * 64 + 63) > qw;

        f32x4 sacc[2][4];
#pragma unroll
        for (int r2 = 0; r2 < 2; ++r2)
#pragma unroll
          for (int n = 0; n < 4; ++n) sacc[r2][n] = (f32x4){0.f, 0.f, 0.f, 0.f};
#pragma unroll
        for (int kk = 0; kk < 4; ++kk) {
#pragma unroll
          for (int n = 0; n < 4; ++n) {
            bf16x8 kf = *(const bf16x8*)&Ks[(n * 16 + fr) * 128 + (((kk * 4 + fq) ^ (fr & 7)) * 8)];
            sacc[0][n] = __builtin_amdgcn_mfma_f32_16x16x32_bf16(kf, qf[0][kk], sacc[0][n], 0, 0, 0);
            sacc[1][n] = __builtin_amdgcn_mfma_f32_16x16x32_bf16(kf, qf[1][kk], sacc[1][n], 0, 0, 0);
          }
        }

#pragma unroll
        for (int r2 = 0; r2 < 2; ++r2) {
          const int qg = qw + r2 * 16 + fr;
          float sv[4][4];
#pragma unroll
          for (int n = 0; n < 4; ++n)
#pragma unroll
            for (int j = 0; j < 4; ++j) {
              float s = sacc[r2][n][j];
              if (diag && (kt * 64 + n * 16 + fq * 4 + j) > qg) s = -__builtin_inff();
              sv[n][j] = s;
            }
          float pmax = sv[0][0];
#pragma unroll
          for (int n = 0; n < 4; ++n)
#pragma unroll
            for (int j = 0; j < 4; ++j) pmax = fmaxf(pmax, sv[n][j]);
          pmax = fmaxf(pmax, __shfl_xor(pmax, 16, 64));
          pmax = fmaxf(pmax, __shfl_xor(pmax, 32, 64));

          const bool nof = __all(pmax <= m_[r2] + 8.f);
          const float mn = nof ? m_[r2] : fmaxf(m_[r2], pmax);
          float ps = 0.f;
#pragma unroll
          for (int n = 0; n < 4; ++n) {
            union { __hip_bfloat16 hh[4]; uint2 u; } pkk;
#pragma unroll
            for (int j = 0; j < 4; ++j) {
              float p = __expf(sv[n][j] - mn);
              ps += p;
              pkk.hh[j] = __float2bfloat16(p);
            }
            *(uint2*)&Psw[(r2 * 16 + fr) * 72 + n * 16 + fq * 4] = pkk.u;
          }
          ps += __shfl_xor(ps, 16, 64);
          ps += __shfl_xor(ps, 32, 64);

          if (!nof) {
            const float alpha = __expf(m_[r2] - mn);
            l_[r2] = l_[r2] * alpha + ps;
            m_[r2] = mn;
            float a0 = __shfl(alpha, fq * 4 + 0, 64);
            float a1 = __shfl(alpha, fq * 4 + 1, 64);
            float a2 = __shfl(alpha, fq * 4 + 2, 64);
            float a3 = __shfl(alpha, fq * 4 + 3, 64);
#pragma unroll
            for (int nd = 0; nd < 8; ++nd) {
              oacc[r2][nd][0] *= a0; oacc[r2][nd][1] *= a1;
              oacc[r2][nd][2] *= a2; oacc[r2][nd][3] *= a3;
            }
          } else {
            l_[r2] += ps;
          }
        }

#pragma unroll
        for (int kk2 = 0; kk2 < 2; ++kk2) {
          bf16x8 pa0 = *(const bf16x8*)&Psw[(0 * 16 + fr) * 72 + kk2 * 32 + fq * 8];
          bf16x8 pa1 = *(const bf16x8*)&Psw[(1 * 16 + fr) * 72 + kk2 * 32 + fq * 8];
#pragma unroll
          for (int nd = 0; nd < 8; ++nd) {
            bf16x8 vf = *(const bf16x8*)&Vts[(nd * 16 + fr) * 64 + (((kk2 * 4 + fq) ^ (fr & 7)) * 8)];
            oacc[0][nd] = __builtin_amdgcn_mfma_f32_16x16x32_bf16(pa0, vf, oacc[0][nd], 0, 0, 0);
            oacc[1][nd] = __builtin_amdgcn_mfma_f32_16x16x32_bf16(pa1, vf, oacc[1][nd], 0, 0, 0);
          }
        }
      }

      __syncthreads();
      cur ^= 1;
    }

    float i0 = 1.0f / l_[0], i1 = 1.0f / l_[1];
    float inv4[2][4];
#pragma unroll
    for (int j = 0; j < 4; ++j) {
      inv4[0][j] = __shfl(i0, fq * 4 + j, 64);
      inv4[1][j] = __shfl(i1, fq * 4 + j, 64);
    }
#pragma unroll
    for (int r2 = 0; r2 < 2; ++r2)
#pragma unroll
      for (int nd = 0; nd < 8; ++nd)
#pragma unroll
        for (int j = 0; j < 4; ++j)
          Os[(w * 32 + r2 * 16 + fq * 4 + j) * 136 + nd * 16 + fr] =
              __float2bfloat16(oacc[r2][nd][j] * inv4[r2][j]);
    __syncthreads();
#pragma unroll
    for (int it = 0; it < 8; ++it) {
      int i = it * 256 + tid;
      int row = i >> 4, ch = i & 15;
      *(bf16x8*)&O[(size_t)(b * PS + q0 + row) * PE + h * 128 + ch * 8] =
          *(const bf16x8*)&Os[row * 136 + ch * 8];
    }
  }
}

// ---------------------------------------------------------------------------
extern "C" void kernel_launch(void* const* d_in, const int* in_sizes, int n_in,
                              void* d_out, int out_size, void* d_ws, size_t ws_size,
                              hipStream_t stream) {
  const float* x     = (const float*)d_in[0];
  const float* Wqkvh = (const float*)d_in[1];
  const float* Wout  = (const float*)d_in[2];
  float* out = (float*)d_out;

  char* wsb = (char*)d_ws;
  __hip_bfloat16* proj = (__hip_bfloat16*)wsb;          // [4096][6144] bf16
  wsb += (size_t)PM * PQKV * 2;
  __hip_bfloat16* xb = (__hip_bfloat16*)wsb;            // reused as attn out
  wsb += (size_t)PM * PE * 2;
  __hip_bfloat16* Wq_t = (__hip_bfloat16*)wsb;
  wsb += (size_t)PQKV * PE * 2;
  __hip_bfloat16* Wout_t = (__hip_bfloat16*)wsb;
  wsb += (size_t)PE * PE * 2;
  __hip_bfloat16* Vtp = (__hip_bfloat16*)wsb;           // [32][128][2048]
  wsb += (size_t)PB * PH * PD * PS * 2;
  float* hgbuf = (float*)wsb;
  wsb += (size_t)PB * PH * PS * 4;
  float* csum = (float*)wsb;

  // 0) casts / weight transposes
  cast_f32_bf16<<<(PM * PE / 4 + 255) / 256, 256, 0, stream>>>(x, xb, PM * PE / 4);
  transpose_cast<<<dim3(PQKV / 32, PE / 32), 256, 0, stream>>>(Wqkvh, Wq_t, PN_PROJ, PE, 0);
  transpose_cast<<<dim3(PE / 32, PE / 32), 256, 0, stream>>>(Wout, Wout_t, PE, PE, 0);

  // 1) proj = x @ W_qkvh[:, :6144] (bf16 out) — BK=64 counted-vmcnt GEMM,
  //    128x384 tile, grid 512 = 2 exact rounds, wave tile 64x96 (cap 72%)
  gemm_cs2<128, 384, 2, 4, __hip_bfloat16>
      <<<dim3((PM / 128) * (PQKV / 384)), 512, 0, stream>>>(
          xb, Wq_t, proj, PE, PE, PE, PQKV, PQKV / 384);

  // 2) gate head + causal weighted cumsum (bf16 in place, pre-scaled)
  hg_from_x<<<PM, 256, 0, stream>>>(x, Wqkvh, hgbuf);
  kc_pass1<<<PB * PH * 16, 128, 0, stream>>>(proj, hgbuf, csum);
  kc_pass2<<<PB * PH * 16, 128, 0, stream>>>(proj, hgbuf, csum);

  // 3) V^T pack + MFMA flash attention -> xb
  vt_pack<<<PB * PH * 32, 256, 0, stream>>>(proj, Vtp);
  __hip_bfloat16* Ob = xb;
  attn_mfma<<<PB * PH * 8, 256, 0, stream>>>(proj, Vtp, Ob);

  // 4) out = Oattn @ W_out (fp32 out) — 128x256 tile, grid 256 = 1 round
  gemm_cs2<128, 256, 2, 4, float>
      <<<dim3((PM / 128) * (PE / 256)), 512, 0, stream>>>(
          Ob, Wout_t, out, PE, PE, PE, PE, PE / 256);
}